// Round 2
// baseline (771.658 us; speedup 1.0000x reference)
//
#include <hip/hip_runtime.h>

#define N_NODES 10000
#define N_EDGES 320000
#define DIM_IN 128
#define HID 256
#define OUT_D 128
#define NG 64

// ---------------------------------------------------------------- utilities

__global__ __launch_bounds__(256) void zero_kernel(unsigned int* __restrict__ p, int n) {
    int i = blockIdx.x * 256 + threadIdx.x;
    if (i < n) p[i] = 0u;
}

// ---------------------------------------------------------------- CSR build

__global__ __launch_bounds__(256) void hist_kernel(const int* __restrict__ dst,
                                                   int* __restrict__ cnt, int n) {
    int i = blockIdx.x * 256 + threadIdx.x;
    if (i < n) atomicAdd(&cnt[dst[i]], 1);
}

__global__ __launch_bounds__(1024) void scan_kernel(const int* __restrict__ cnt,
                                                    int* __restrict__ rowptr, int n) {
    __shared__ int lds[1024];
    int t = threadIdx.x;
    const int CH = 10;                       // 1024*10 >= 10000
    int base = t * CH;
    int loc[CH];
    int s = 0;
#pragma unroll
    for (int i = 0; i < CH; ++i) {
        int v = (base + i < n) ? cnt[base + i] : 0;
        loc[i] = s;
        s += v;
    }
    lds[t] = s;
    __syncthreads();
    for (int off = 1; off < 1024; off <<= 1) {
        int v = (t >= off) ? lds[t - off] : 0;
        __syncthreads();
        lds[t] += v;
        __syncthreads();
    }
    int excl = lds[t] - s;                   // exclusive prefix of partials
#pragma unroll
    for (int i = 0; i < CH; ++i)
        if (base + i < n) rowptr[base + i] = excl + loc[i];
    if (t == 1023) rowptr[n] = lds[1023];
}

__global__ __launch_bounds__(256) void scatter_kernel(const int* __restrict__ dst,
                                                      const int* __restrict__ rowptr,
                                                      int* __restrict__ fill,
                                                      int* __restrict__ eids, int n) {
    int i = blockIdx.x * 256 + threadIdx.x;
    if (i < n) {
        int d = dst[i];
        int pos = rowptr[d] + atomicAdd(&fill[d], 1);
        eids[pos] = i;
    }
}

// ------------------------------------------------- SAGE aggregate (gather)
// agg[n][c] = mean_{e: dst[e]==n} relu(h[src[e]][c] + attr[e]*We[c] + be[c])
// one wave per node, lane owns 4 channels (C fixed = 256)

__global__ __launch_bounds__(64) void agg_kernel(const float* __restrict__ h,
                                                 const int* __restrict__ src,
                                                 const float* __restrict__ eattr,
                                                 const int* __restrict__ rowptr,
                                                 const int* __restrict__ eids,
                                                 const float* __restrict__ we,
                                                 const float* __restrict__ be,
                                                 float* __restrict__ agg) {
    int n = blockIdx.x;
    int c4 = threadIdx.x << 2;
    float4 wv = *(const float4*)&we[c4];
    float4 bv = *(const float4*)&be[c4];
    int p0 = rowptr[n], p1 = rowptr[n + 1];
    float ax = 0.f, ay = 0.f, az = 0.f, aw = 0.f;
    for (int p = p0; p < p1; ++p) {
        int e = eids[p];
        int s = src[e];
        float a = eattr[e];
        float4 hv = *(const float4*)&h[(size_t)s * HID + c4];
        float vx = hv.x + a * wv.x + bv.x;
        float vy = hv.y + a * wv.y + bv.y;
        float vz = hv.z + a * wv.z + bv.z;
        float vw = hv.w + a * wv.w + bv.w;
        ax += fmaxf(vx, 0.f);
        ay += fmaxf(vy, 0.f);
        az += fmaxf(vz, 0.f);
        aw += fmaxf(vw, 0.f);
    }
    int deg = p1 - p0;
    float inv = 1.f / (float)(deg > 0 ? deg : 1);
    float4 o;
    o.x = ax * inv; o.y = ay * inv; o.z = az * inv; o.w = aw * inv;
    *(float4*)&agg[(size_t)n * HID + c4] = o;
}

// ---------------------------------------------------------------- GEMM
// C[M,N] = act( A@B (+ A2@B2) + bias ),  A:[M,K] B:[K,N] row-major.
// 64x64 block tile, 128 threads (16 colgrp x 8 rowgrp), 8x4 per thread, BK=32.
// 8x4/thread: 48 B LDS per 64 FLOP (0.75 B/FLOP, A-frag 16-way broadcast)
// vs 1.0 B/FLOP for the old 4x4 — lifts the LDS-read-bound ceiling ~40%.
// A staged transposed in LDS (stride 68).

__device__ __forceinline__ float4 ldg4g(const float* __restrict__ p, int r, int c,
                                        int M, int ld) {
    if (r < M) return *(const float4*)(p + (size_t)r * ld + c);
    return make_float4(0.f, 0.f, 0.f, 0.f);
}

template <int ACT>  // 0 = none, 1 = relu, 2 = leaky(0.01)
__global__ __launch_bounds__(128) void gemm64(const float* __restrict__ A,
                                              const float* __restrict__ B,
                                              const float* __restrict__ A2,
                                              const float* __restrict__ B2,
                                              const float* __restrict__ bias,
                                              float* __restrict__ C,
                                              int M, int N, int K) {
    __shared__ float As[32][68];   // [k][row], padded
    __shared__ float Bs[32][64];   // [k][col]
    int tid = threadIdx.x;         // 0..127
    int tc = tid & 15;             // col group: 4 cols
    int tr = tid >> 4;             // 0..7 row group: 8 rows
    int row0 = blockIdx.y << 6, col0 = blockIdx.x << 6;

    float acc[8][4] = {};
    const float* Ap = A;
    const float* Bp = B;
    int npass = (A2 != nullptr) ? 2 : 1;

    for (int pass = 0; pass < npass; ++pass) {
        for (int k0 = 0; k0 < K; k0 += 32) {
            float4 a[4], b[4];
#pragma unroll
            for (int p = 0; p < 4; ++p) {
                int l = tid + (p << 7);
                int arow = l >> 3, ak = (l & 7) << 2;       // A: 64r x 8 kq
                a[p] = ldg4g(Ap, row0 + arow, k0 + ak, M, K);
                int bk = l >> 4, bc = (l & 15) << 2;        // B: 32k x 16 cq
                b[p] = *(const float4*)&Bp[(size_t)(k0 + bk) * N + col0 + bc];
            }
            __syncthreads();
#pragma unroll
            for (int p = 0; p < 4; ++p) {
                int l = tid + (p << 7);
                int arow = l >> 3, ak = (l & 7) << 2;
                As[ak + 0][arow] = a[p].x;
                As[ak + 1][arow] = a[p].y;
                As[ak + 2][arow] = a[p].z;
                As[ak + 3][arow] = a[p].w;
                int bk = l >> 4, bc = (l & 15) << 2;
                *(float4*)&Bs[bk][bc] = b[p];
            }
            __syncthreads();
#pragma unroll
            for (int k = 0; k < 32; ++k) {
                float4 a0 = *(const float4*)&As[k][tr << 3];
                float4 a1 = *(const float4*)&As[k][(tr << 3) + 4];
                float4 bv = *(const float4*)&Bs[k][tc << 2];
                acc[0][0] += a0.x * bv.x; acc[0][1] += a0.x * bv.y;
                acc[0][2] += a0.x * bv.z; acc[0][3] += a0.x * bv.w;
                acc[1][0] += a0.y * bv.x; acc[1][1] += a0.y * bv.y;
                acc[1][2] += a0.y * bv.z; acc[1][3] += a0.y * bv.w;
                acc[2][0] += a0.z * bv.x; acc[2][1] += a0.z * bv.y;
                acc[2][2] += a0.z * bv.z; acc[2][3] += a0.z * bv.w;
                acc[3][0] += a0.w * bv.x; acc[3][1] += a0.w * bv.y;
                acc[3][2] += a0.w * bv.z; acc[3][3] += a0.w * bv.w;
                acc[4][0] += a1.x * bv.x; acc[4][1] += a1.x * bv.y;
                acc[4][2] += a1.x * bv.z; acc[4][3] += a1.x * bv.w;
                acc[5][0] += a1.y * bv.x; acc[5][1] += a1.y * bv.y;
                acc[5][2] += a1.y * bv.z; acc[5][3] += a1.y * bv.w;
                acc[6][0] += a1.z * bv.x; acc[6][1] += a1.z * bv.y;
                acc[6][2] += a1.z * bv.z; acc[6][3] += a1.z * bv.w;
                acc[7][0] += a1.w * bv.x; acc[7][1] += a1.w * bv.y;
                acc[7][2] += a1.w * bv.z; acc[7][3] += a1.w * bv.w;
            }
        }
        Ap = A2;
        Bp = B2;
    }

    float4 bb = *(const float4*)&bias[col0 + (tc << 2)];
#pragma unroll
    for (int i = 0; i < 8; ++i) {
        int r = row0 + (tr << 3) + i;
        if (r < M) {
            float4 o;
            o.x = acc[i][0] + bb.x; o.y = acc[i][1] + bb.y;
            o.z = acc[i][2] + bb.z; o.w = acc[i][3] + bb.w;
            if (ACT == 1) {
                o.x = fmaxf(o.x, 0.f); o.y = fmaxf(o.y, 0.f);
                o.z = fmaxf(o.z, 0.f); o.w = fmaxf(o.w, 0.f);
            } else if (ACT == 2) {
                o.x = (o.x >= 0.f) ? o.x : 0.01f * o.x;
                o.y = (o.y >= 0.f) ? o.y : 0.01f * o.y;
                o.z = (o.z >= 0.f) ? o.z : 0.01f * o.z;
                o.w = (o.w >= 0.f) ? o.w : 0.01f * o.w;
            }
            *(float4*)&C[(size_t)r * N + col0 + (tc << 2)] = o;
        }
    }
}

// ---------------------------------------------------------------- pooling

__global__ __launch_bounds__(256) void count_kernel(const int* __restrict__ batch,
                                                    int* __restrict__ gcnt, int n) {
    int i = blockIdx.x * 256 + threadIdx.x;
    if (i < n) atomicAdd(&gcnt[batch[i]], 1);
}

// batch is sorted: per-block segmented partial sums, few atomics.
// grid 80 x 128 threads; each block owns 125 consecutive rows; thread = channel.
__global__ __launch_bounds__(128) void pool_kernel(const float* __restrict__ h,
                                                   const int* __restrict__ batch,
                                                   float* __restrict__ gsum) {
    int c = threadIdx.x;                    // 0..127
    int r0 = blockIdx.x * 125, r1 = r0 + 125;
    float acc = 0.f;
    int cur = batch[r0];
    for (int r = r0; r < r1; ++r) {
        int b = batch[r];
        if (b != cur) {
            atomicAdd(&gsum[cur * OUT_D + c], acc);
            acc = 0.f;
            cur = b;
        }
        acc += h[(size_t)r * OUT_D + c];
    }
    atomicAdd(&gsum[cur * OUT_D + c], acc);
}

// t2[r][c] = sum_k (gsum[r][k]/max(cnt,1)) * ohw[k][c] + ohb[c];  64 blocks x 256
__global__ __launch_bounds__(256) void pooled_mm(const float* __restrict__ gsum,
                                                 const int* __restrict__ gcnt,
                                                 const float* __restrict__ ohw,
                                                 const float* __restrict__ ohb,
                                                 float* __restrict__ t2) {
    __shared__ float gm[OUT_D];
    int r = blockIdx.x;
    int c = threadIdx.x;
    if (c < OUT_D) {
        int ct = gcnt[r];
        gm[c] = gsum[r * OUT_D + c] / (float)(ct > 0 ? ct : 1);
    }
    __syncthreads();
    float acc = ohb[c];
    for (int k = 0; k < OUT_D; ++k) acc += gm[k] * ohw[k * HID + c];
    t2[r * HID + c] = acc;
}

// batchnorm over 64 rows + leaky + final linear [256->1] + relu
__global__ __launch_bounds__(256) void finalize_kernel(const float* __restrict__ t2,
                                                       const float* __restrict__ gamma,
                                                       const float* __restrict__ beta,
                                                       const float* __restrict__ h1w,
                                                       const float* __restrict__ h1b,
                                                       float* __restrict__ out) {
    __shared__ float tl[NG][HID];
    int c = threadIdx.x;                    // channel 0..255
    float mean = 0.f;
    for (int r = 0; r < NG; ++r) mean += t2[r * HID + c];
    mean *= (1.f / (float)NG);
    float var = 0.f;
    for (int r = 0; r < NG; ++r) {
        float d = t2[r * HID + c] - mean;
        var += d * d;
    }
    var *= (1.f / (float)NG);
    float sc = gamma[c] / sqrtf(var + 1e-5f);
    float sh = beta[c] - mean * sc;
    for (int r = 0; r < NG; ++r) {
        float v = t2[r * HID + c] * sc + sh;
        tl[r][c] = (v >= 0.f) ? v : 0.01f * v;
    }
    __syncthreads();
    int wid = c >> 6, lane = c & 63;
    float4 wv = *(const float4*)&h1w[lane << 2];
    float b0 = h1b[0];
    for (int row = wid; row < NG; row += 4) {
        float4 v = *(const float4*)&tl[row][lane << 2];
        float s = v.x * wv.x + v.y * wv.y + v.z * wv.z + v.w * wv.w;
#pragma unroll
        for (int off = 32; off >= 1; off >>= 1) s += __shfl_xor(s, off);
        if (lane == 0) out[row] = fmaxf(s + b0, 0.f);
    }
}

// ---------------------------------------------------------------- driver

extern "C" void kernel_launch(void* const* d_in, const int* in_sizes, int n_in,
                              void* d_out, int out_size, void* d_ws, size_t ws_size,
                              hipStream_t stream) {
    const float* x        = (const float*)d_in[0];
    const int*   ei       = (const int*)d_in[1];
    const float* eattr    = (const float*)d_in[2];
    const int*   batch    = (const int*)d_in[3];
    const float* prelin_w = (const float*)d_in[4];
    const float* prelin_b = (const float*)d_in[5];
    const float* c1_wl = (const float*)d_in[6],  *c1_bl = (const float*)d_in[7];
    const float* c1_wr = (const float*)d_in[8],  *c1_we = (const float*)d_in[9];
    const float* c1_be = (const float*)d_in[10];
    const float* c2_wl = (const float*)d_in[11], *c2_bl = (const float*)d_in[12];
    const float* c2_wr = (const float*)d_in[13], *c2_we = (const float*)d_in[14];
    const float* c2_be = (const float*)d_in[15];
    const float* c3_wl = (const float*)d_in[16], *c3_bl = (const float*)d_in[17];
    const float* c3_wr = (const float*)d_in[18], *c3_we = (const float*)d_in[19];
    const float* c3_be = (const float*)d_in[20];
    const float* hh1_w = (const float*)d_in[21], *hh1_b = (const float*)d_in[22];
    const float* hh2_w = (const float*)d_in[23], *hh2_b = (const float*)d_in[24];
    const float* oo_w  = (const float*)d_in[25], *oo_b  = (const float*)d_in[26];
    const float* oh_w  = (const float*)d_in[27], *oh_b  = (const float*)d_in[28];
    const float* h1_w  = (const float*)d_in[29], *h1_b  = (const float*)d_in[30];
    const float* bn_g  = (const float*)d_in[31], *bn_b  = (const float*)d_in[32];
    float* out = (float*)d_out;

    const int* srcp = ei;               // edge_index[0]
    const int* dstp = ei + N_EDGES;     // edge_index[1]

    // workspace layout (4-byte words)
    float* ws    = (float*)d_ws;
    float* hA    = ws;                              // [10000,256]
    float* hB    = hA + 2560000;                    // [10000,256]
    float* AGG   = hB + 2560000;                    // [10000,256]
    float* t2    = AGG + 2560000;                   // [64,256]
    float* gsum  = t2 + NG * HID;                   // [64,128]
    int*   gcnt  = (int*)(gsum + NG * OUT_D);       // [64]
    int*   rowptr = gcnt + NG;                      // [10001]
    int*   cnt   = rowptr + (N_NODES + 1);          // [10000]
    int*   fill  = cnt + N_NODES;                   // [10000]
    int*   eids  = fill + N_NODES;                  // [320000]

    // zero the counters (ws is poisoned 0xAA every call)
    zero_kernel<<<(2 * N_NODES + 255) / 256, 256, 0, stream>>>((unsigned int*)cnt, 2 * N_NODES);
    zero_kernel<<<(NG * OUT_D + NG + 255) / 256, 256, 0, stream>>>((unsigned int*)gsum, NG * OUT_D + NG);

    // CSR build (edge_index is identical for all three convs)
    hist_kernel<<<(N_EDGES + 255) / 256, 256, 0, stream>>>(dstp, cnt, N_EDGES);
    scan_kernel<<<1, 1024, 0, stream>>>(cnt, rowptr, N_NODES);
    scatter_kernel<<<(N_EDGES + 255) / 256, 256, 0, stream>>>(dstp, rowptr, fill, eids, N_EDGES);

    dim3 blk(128);
    dim3 g256(HID / 64, (N_NODES + 63) / 64);    // N=256 outputs
    dim3 g128(OUT_D / 64, (N_NODES + 63) / 64);  // N=128 outputs

    // h = relu(x @ prelin_w + b)
    gemm64<1><<<g256, blk, 0, stream>>>(x, prelin_w, nullptr, nullptr, prelin_b, hA,
                                        N_NODES, HID, DIM_IN);
    // conv1
    agg_kernel<<<N_NODES, 64, 0, stream>>>(hA, srcp, eattr, rowptr, eids, c1_we, c1_be, AGG);
    gemm64<1><<<g256, blk, 0, stream>>>(AGG, c1_wl, hA, c1_wr, c1_bl, hB, N_NODES, HID, HID);
    // hh1
    gemm64<2><<<g256, blk, 0, stream>>>(hB, hh1_w, nullptr, nullptr, hh1_b, hA, N_NODES, HID, HID);
    // conv2
    agg_kernel<<<N_NODES, 64, 0, stream>>>(hA, srcp, eattr, rowptr, eids, c2_we, c2_be, AGG);
    gemm64<1><<<g256, blk, 0, stream>>>(AGG, c2_wl, hA, c2_wr, c2_bl, hB, N_NODES, HID, HID);
    // hh2
    gemm64<2><<<g256, blk, 0, stream>>>(hB, hh2_w, nullptr, nullptr, hh2_b, hA, N_NODES, HID, HID);
    // conv3 (HID -> OUT)
    agg_kernel<<<N_NODES, 64, 0, stream>>>(hA, srcp, eattr, rowptr, eids, c3_we, c3_be, AGG);
    gemm64<1><<<g128, blk, 0, stream>>>(AGG, c3_wl, hA, c3_wr, c3_bl, hB, N_NODES, OUT_D, HID);
    // oo
    gemm64<2><<<g128, blk, 0, stream>>>(hB, oo_w, nullptr, nullptr, oo_b, hA, N_NODES, OUT_D, OUT_D);

    // global mean pool + head
    count_kernel<<<(N_NODES + 255) / 256, 256, 0, stream>>>(batch, gcnt, N_NODES);
    pool_kernel<<<80, 128, 0, stream>>>(hA, batch, gsum);
    pooled_mm<<<NG, 256, 0, stream>>>(gsum, gcnt, oh_w, oh_b, t2);
    finalize_kernel<<<1, 256, 0, stream>>>(t2, bn_g, bn_b, h1_w, h1_b, out);
}

// Round 6
// 624.724 us; speedup vs baseline: 1.2352x; 1.2352x over previous
//
#include <hip/hip_runtime.h>

#define N_NODES 10000
#define N_EDGES 320000
#define DIM_IN 128
#define HID 256
#define OUT_D 128
#define NG 64

// ---------------------------------------------------------------- utilities

__global__ __launch_bounds__(256) void zero_kernel(unsigned int* __restrict__ p, int n) {
    int i = blockIdx.x * 256 + threadIdx.x;
    if (i < n) p[i] = 0u;
}

// ---------------------------------------------------------------- CSR build

__global__ __launch_bounds__(256) void hist_kernel(const int* __restrict__ dst,
                                                   int* __restrict__ cnt, int n) {
    int i = blockIdx.x * 256 + threadIdx.x;
    if (i < n) atomicAdd(&cnt[dst[i]], 1);
}

__global__ __launch_bounds__(1024) void scan_kernel(const int* __restrict__ cnt,
                                                    int* __restrict__ rowptr, int n) {
    __shared__ int lds[1024];
    int t = threadIdx.x;
    const int CH = 10;                       // 1024*10 >= 10000
    int base = t * CH;
    int loc[CH];
    int s = 0;
#pragma unroll
    for (int i = 0; i < CH; ++i) {
        int v = (base + i < n) ? cnt[base + i] : 0;
        loc[i] = s;
        s += v;
    }
    lds[t] = s;
    __syncthreads();
    for (int off = 1; off < 1024; off <<= 1) {
        int v = (t >= off) ? lds[t - off] : 0;
        __syncthreads();
        lds[t] += v;
        __syncthreads();
    }
    int excl = lds[t] - s;                   // exclusive prefix of partials
#pragma unroll
    for (int i = 0; i < CH; ++i)
        if (base + i < n) rowptr[base + i] = excl + loc[i];
    if (t == 1023) rowptr[n] = lds[1023];
}

// also materializes dst-sorted srcs/attrs so agg has ONE indirection level
__global__ __launch_bounds__(256) void scatter_kernel(const int* __restrict__ src,
                                                      const int* __restrict__ dst,
                                                      const float* __restrict__ eattr,
                                                      const int* __restrict__ rowptr,
                                                      int* __restrict__ fill,
                                                      int* __restrict__ srcs,
                                                      float* __restrict__ attrs, int n) {
    int i = blockIdx.x * 256 + threadIdx.x;
    if (i < n) {
        int d = dst[i];
        int pos = rowptr[d] + atomicAdd(&fill[d], 1);
        srcs[pos] = src[i];
        attrs[pos] = eattr[i];
    }
}

// ------------------------------------------------- SAGE aggregate (gather)
// agg[n][c] = mean_{e: dst[e]==n} relu(h[src[e]][c] + attr[e]*We[c] + be[c])
// 256 threads = 4 waves = 4 nodes per block; lane owns 4 channels.
// 2-way edge unroll: two independent h-row gathers in flight per wave.

__global__ __launch_bounds__(256) void agg_kernel(const float* __restrict__ h,
                                                  const int* __restrict__ srcs,
                                                  const float* __restrict__ attrs,
                                                  const int* __restrict__ rowptr,
                                                  const float* __restrict__ we,
                                                  const float* __restrict__ be,
                                                  float* __restrict__ agg) {
    int n = (blockIdx.x << 2) + (threadIdx.x >> 6);
    int c4 = (threadIdx.x & 63) << 2;
    float4 wv = *(const float4*)&we[c4];
    float4 bv = *(const float4*)&be[c4];
    int p0 = rowptr[n], p1 = rowptr[n + 1];
    float4 a0 = make_float4(0.f, 0.f, 0.f, 0.f);
    float4 a1 = make_float4(0.f, 0.f, 0.f, 0.f);
    int p = p0;
    for (; p + 2 <= p1; p += 2) {
        int s0 = srcs[p], s1 = srcs[p + 1];
        float e0 = attrs[p], e1 = attrs[p + 1];
        float4 h0 = *(const float4*)&h[(size_t)s0 * HID + c4];
        float4 h1 = *(const float4*)&h[(size_t)s1 * HID + c4];
        a0.x += fmaxf(h0.x + e0 * wv.x + bv.x, 0.f);
        a0.y += fmaxf(h0.y + e0 * wv.y + bv.y, 0.f);
        a0.z += fmaxf(h0.z + e0 * wv.z + bv.z, 0.f);
        a0.w += fmaxf(h0.w + e0 * wv.w + bv.w, 0.f);
        a1.x += fmaxf(h1.x + e1 * wv.x + bv.x, 0.f);
        a1.y += fmaxf(h1.y + e1 * wv.y + bv.y, 0.f);
        a1.z += fmaxf(h1.z + e1 * wv.z + bv.z, 0.f);
        a1.w += fmaxf(h1.w + e1 * wv.w + bv.w, 0.f);
    }
    if (p < p1) {
        int s0 = srcs[p];
        float e0 = attrs[p];
        float4 h0 = *(const float4*)&h[(size_t)s0 * HID + c4];
        a0.x += fmaxf(h0.x + e0 * wv.x + bv.x, 0.f);
        a0.y += fmaxf(h0.y + e0 * wv.y + bv.y, 0.f);
        a0.z += fmaxf(h0.z + e0 * wv.z + bv.z, 0.f);
        a0.w += fmaxf(h0.w + e0 * wv.w + bv.w, 0.f);
    }
    int deg = p1 - p0;
    float inv = 1.f / (float)(deg > 0 ? deg : 1);
    float4 o;
    o.x = (a0.x + a1.x) * inv;
    o.y = (a0.y + a1.y) * inv;
    o.z = (a0.z + a1.z) * inv;
    o.w = (a0.w + a1.w) * inv;
    *(float4*)&agg[(size_t)n * HID + c4] = o;
}

// ---------------------------------------------------------------- GEMM
// C[M,N] = act( A@B (+ A2@B2) + bias ),  A:[M,K] B:[K,N] row-major.
// 64x64 tile, 256 threads (16x16), 4x4/thread, BK=32, register prefetch.
// XCD-bijective swizzle in x-major order: each XCD owns contiguous row-bands
// so the A panel stays in its own L2 across the 4 column blocks.

__device__ __forceinline__ float4 ldg4g(const float* __restrict__ p, int r, int c,
                                        int M, int ld) {
    if (r < M) return *(const float4*)(p + (size_t)r * ld + c);
    return make_float4(0.f, 0.f, 0.f, 0.f);
}

template <int ACT>  // 0 = none, 1 = relu, 2 = leaky(0.01)
__global__ __launch_bounds__(256) void gemm64(const float* __restrict__ A,
                                              const float* __restrict__ B,
                                              const float* __restrict__ A2,
                                              const float* __restrict__ B2,
                                              const float* __restrict__ bias,
                                              float* __restrict__ C,
                                              int M, int N, int K) {
    __shared__ float As[32][72];   // [k][row]; stride 72: 16B-aligned, 2-way max
    __shared__ float Bs[32][64];   // [k][col]
    int tid = threadIdx.x;         // 0..255
    int tc = tid & 15;             // col group (4 cols)
    int tr = tid >> 4;             // row group (4 rows)

    // ---- bijective XCD swizzle (m204): xcd = orig%8 gets a contiguous chunk
    int gx = gridDim.x, nwg = gx * gridDim.y;
    int orig = blockIdx.y * gx + blockIdx.x;
    int q = nwg >> 3, r = nwg & 7;
    int xcd = orig & 7, loc = orig >> 3;
    int t = (xcd < r) ? (xcd * (q + 1) + loc) : (r * (q + 1) + (xcd - r) * q + loc);
    int row0 = (t / gx) << 6, col0 = (t % gx) << 6;

    // staging indices
    int arow = tid >> 2;            // 0..63
    int ak8 = (tid & 3) << 3;       // 0,8,16,24
    int bk = tid >> 4;              // 0..15 (two k halves: bk, bk+16)
    int bc = (tid & 15) << 2;       // 0..60

    float acc[4][4] = {};
    const float* APs[2] = {A, A2 ? A2 : A};
    const float* BPs[2] = {B, B2 ? B2 : B};
    int nt = K >> 5;
    int tnt = (A2 != nullptr) ? (nt << 1) : nt;

    // prefetch tile 0
    float4 a0 = ldg4g(APs[0], row0 + arow, ak8, M, K);
    float4 a1 = ldg4g(APs[0], row0 + arow, ak8 + 4, M, K);
    float4 b0 = *(const float4*)&BPs[0][(size_t)bk * N + col0 + bc];
    float4 b1 = *(const float4*)&BPs[0][(size_t)(bk + 16) * N + col0 + bc];

    for (int tt = 0; tt < tnt; ++tt) {
        __syncthreads();
        As[ak8 + 0][arow] = a0.x; As[ak8 + 1][arow] = a0.y;
        As[ak8 + 2][arow] = a0.z; As[ak8 + 3][arow] = a0.w;
        As[ak8 + 4][arow] = a1.x; As[ak8 + 5][arow] = a1.y;
        As[ak8 + 6][arow] = a1.z; As[ak8 + 7][arow] = a1.w;
        *(float4*)&Bs[bk][bc] = b0;
        *(float4*)&Bs[bk + 16][bc] = b1;
        __syncthreads();
        if (tt + 1 < tnt) {
            int tp = tt + 1;
            int ps = (tp >= nt) ? 1 : 0;
            int k0 = (tp - (ps ? nt : 0)) << 5;
            const float* Ax = APs[ps];
            const float* Bx = BPs[ps];
            a0 = ldg4g(Ax, row0 + arow, k0 + ak8, M, K);
            a1 = ldg4g(Ax, row0 + arow, k0 + ak8 + 4, M, K);
            b0 = *(const float4*)&Bx[(size_t)(k0 + bk) * N + col0 + bc];
            b1 = *(const float4*)&Bx[(size_t)(k0 + bk + 16) * N + col0 + bc];
        }
#pragma unroll
        for (int k = 0; k < 32; ++k) {
            float4 av = *(const float4*)&As[k][tr << 2];
            float4 bv = *(const float4*)&Bs[k][tc << 2];
            acc[0][0] += av.x * bv.x; acc[0][1] += av.x * bv.y;
            acc[0][2] += av.x * bv.z; acc[0][3] += av.x * bv.w;
            acc[1][0] += av.y * bv.x; acc[1][1] += av.y * bv.y;
            acc[1][2] += av.y * bv.z; acc[1][3] += av.y * bv.w;
            acc[2][0] += av.z * bv.x; acc[2][1] += av.z * bv.y;
            acc[2][2] += av.z * bv.z; acc[2][3] += av.z * bv.w;
            acc[3][0] += av.w * bv.x; acc[3][1] += av.w * bv.y;
            acc[3][2] += av.w * bv.z; acc[3][3] += av.w * bv.w;
        }
    }

    float4 bb = *(const float4*)&bias[col0 + (tc << 2)];
#pragma unroll
    for (int i = 0; i < 4; ++i) {
        int rr = row0 + (tr << 2) + i;
        if (rr < M) {
            float4 o;
            o.x = acc[i][0] + bb.x; o.y = acc[i][1] + bb.y;
            o.z = acc[i][2] + bb.z; o.w = acc[i][3] + bb.w;
            if (ACT == 1) {
                o.x = fmaxf(o.x, 0.f); o.y = fmaxf(o.y, 0.f);
                o.z = fmaxf(o.z, 0.f); o.w = fmaxf(o.w, 0.f);
            } else if (ACT == 2) {
                o.x = (o.x >= 0.f) ? o.x : 0.01f * o.x;
                o.y = (o.y >= 0.f) ? o.y : 0.01f * o.y;
                o.z = (o.z >= 0.f) ? o.z : 0.01f * o.z;
                o.w = (o.w >= 0.f) ? o.w : 0.01f * o.w;
            }
            *(float4*)&C[(size_t)rr * N + col0 + (tc << 2)] = o;
        }
    }
}

// ---------------------------------------------------------------- pooling

__global__ __launch_bounds__(256) void count_kernel(const int* __restrict__ batch,
                                                    int* __restrict__ gcnt, int n) {
    int i = blockIdx.x * 256 + threadIdx.x;
    if (i < n) atomicAdd(&gcnt[batch[i]], 1);
}

// batch is sorted: per-block segmented partial sums, few atomics.
__global__ __launch_bounds__(128) void pool_kernel(const float* __restrict__ h,
                                                   const int* __restrict__ batch,
                                                   float* __restrict__ gsum) {
    int c = threadIdx.x;                    // 0..127
    int r0 = blockIdx.x * 125, r1 = r0 + 125;
    float acc = 0.f;
    int cur = batch[r0];
    for (int r = r0; r < r1; ++r) {
        int b = batch[r];
        if (b != cur) {
            atomicAdd(&gsum[cur * OUT_D + c], acc);
            acc = 0.f;
            cur = b;
        }
        acc += h[(size_t)r * OUT_D + c];
    }
    atomicAdd(&gsum[cur * OUT_D + c], acc);
}

// t2[r][c] = sum_k (gsum[r][k]/max(cnt,1)) * ohw[k][c] + ohb[c];  64 blocks x 256
__global__ __launch_bounds__(256) void pooled_mm(const float* __restrict__ gsum,
                                                 const int* __restrict__ gcnt,
                                                 const float* __restrict__ ohw,
                                                 const float* __restrict__ ohb,
                                                 float* __restrict__ t2) {
    __shared__ float gm[OUT_D];
    int r = blockIdx.x;
    int c = threadIdx.x;
    if (c < OUT_D) {
        int ct = gcnt[r];
        gm[c] = gsum[r * OUT_D + c] / (float)(ct > 0 ? ct : 1);
    }
    __syncthreads();
    float acc = ohb[c];
    for (int k = 0; k < OUT_D; ++k) acc += gm[k] * ohw[k * HID + c];
    t2[r * HID + c] = acc;
}

// batchnorm over 64 rows + leaky + final linear [256->1] + relu
__global__ __launch_bounds__(256) void finalize_kernel(const float* __restrict__ t2,
                                                       const float* __restrict__ gamma,
                                                       const float* __restrict__ beta,
                                                       const float* __restrict__ h1w,
                                                       const float* __restrict__ h1b,
                                                       float* __restrict__ out) {
    __shared__ float tl[NG][HID];
    int c = threadIdx.x;                    // channel 0..255
    float mean = 0.f;
    for (int r = 0; r < NG; ++r) mean += t2[r * HID + c];
    mean *= (1.f / (float)NG);
    float var = 0.f;
    for (int r = 0; r < NG; ++r) {
        float d = t2[r * HID + c] - mean;
        var += d * d;
    }
    var *= (1.f / (float)NG);
    float sc = gamma[c] / sqrtf(var + 1e-5f);
    float sh = beta[c] - mean * sc;
    for (int r = 0; r < NG; ++r) {
        float v = t2[r * HID + c] * sc + sh;
        tl[r][c] = (v >= 0.f) ? v : 0.01f * v;
    }
    __syncthreads();
    int wid = c >> 6, lane = c & 63;
    float4 wv = *(const float4*)&h1w[lane << 2];
    float b0 = h1b[0];
    for (int row = wid; row < NG; row += 4) {
        float4 v = *(const float4*)&tl[row][lane << 2];
        float s = v.x * wv.x + v.y * wv.y + v.z * wv.z + v.w * wv.w;
#pragma unroll
        for (int off = 32; off >= 1; off >>= 1) s += __shfl_xor(s, off);
        if (lane == 0) out[row] = fmaxf(s + b0, 0.f);
    }
}

// ---------------------------------------------------------------- driver

extern "C" void kernel_launch(void* const* d_in, const int* in_sizes, int n_in,
                              void* d_out, int out_size, void* d_ws, size_t ws_size,
                              hipStream_t stream) {
    const float* x        = (const float*)d_in[0];
    const int*   ei       = (const int*)d_in[1];
    const float* eattr    = (const float*)d_in[2];
    const int*   batch    = (const int*)d_in[3];
    const float* prelin_w = (const float*)d_in[4];
    const float* prelin_b = (const float*)d_in[5];
    const float* c1_wl = (const float*)d_in[6],  *c1_bl = (const float*)d_in[7];
    const float* c1_wr = (const float*)d_in[8],  *c1_we = (const float*)d_in[9];
    const float* c1_be = (const float*)d_in[10];
    const float* c2_wl = (const float*)d_in[11], *c2_bl = (const float*)d_in[12];
    const float* c2_wr = (const float*)d_in[13], *c2_we = (const float*)d_in[14];
    const float* c2_be = (const float*)d_in[15];
    const float* c3_wl = (const float*)d_in[16], *c3_bl = (const float*)d_in[17];
    const float* c3_wr = (const float*)d_in[18], *c3_we = (const float*)d_in[19];
    const float* c3_be = (const float*)d_in[20];
    const float* hh1_w = (const float*)d_in[21], *hh1_b = (const float*)d_in[22];
    const float* hh2_w = (const float*)d_in[23], *hh2_b = (const float*)d_in[24];
    const float* oo_w  = (const float*)d_in[25], *oo_b  = (const float*)d_in[26];
    const float* oh_w  = (const float*)d_in[27], *oh_b  = (const float*)d_in[28];
    const float* h1_w  = (const float*)d_in[29], *h1_b  = (const float*)d_in[30];
    const float* bn_g  = (const float*)d_in[31], *bn_b  = (const float*)d_in[32];
    float* out = (float*)d_out;

    const int* srcp = ei;               // edge_index[0]
    const int* dstp = ei + N_EDGES;     // edge_index[1]

    // workspace layout (4-byte words); ~33.4 MB total
    float* ws    = (float*)d_ws;
    float* hA    = ws;                              // [10000,256]
    float* hB    = hA + 2560000;                    // [10000,256]
    float* AGG   = hB + 2560000;                    // [10000,256]
    float* t2    = AGG + 2560000;                   // [64,256]
    float* gsum  = t2 + NG * HID;                   // [64,128]
    int*   gcnt  = (int*)(gsum + NG * OUT_D);       // [64]
    int*   rowptr = gcnt + NG;                      // [10001]
    int*   cnt   = rowptr + (N_NODES + 1);          // [10000]
    int*   fill  = cnt + N_NODES;                   // [10000]
    int*   srcs  = fill + N_NODES;                  // [320000] dst-sorted src
    float* attrs = (float*)(srcs + N_EDGES);        // [320000] dst-sorted attr

    // zero the counters (ws is poisoned 0xAA every call)
    zero_kernel<<<(2 * N_NODES + 255) / 256, 256, 0, stream>>>((unsigned int*)cnt, 2 * N_NODES);
    zero_kernel<<<(NG * OUT_D + NG + 255) / 256, 256, 0, stream>>>((unsigned int*)gsum, NG * OUT_D + NG);

    // CSR build (edge_index is identical for all three convs)
    hist_kernel<<<(N_EDGES + 255) / 256, 256, 0, stream>>>(dstp, cnt, N_EDGES);
    scan_kernel<<<1, 1024, 0, stream>>>(cnt, rowptr, N_NODES);
    scatter_kernel<<<(N_EDGES + 255) / 256, 256, 0, stream>>>(srcp, dstp, eattr, rowptr,
                                                              fill, srcs, attrs, N_EDGES);

    dim3 blk(256);
    dim3 g256(HID / 64, (N_NODES + 63) / 64);    // N=256 outputs
    dim3 g128(OUT_D / 64, (N_NODES + 63) / 64);  // N=128 outputs
    dim3 ablk(256);
    int agrid = N_NODES / 4;                      // 4 nodes per block

    // h = relu(x @ prelin_w + b)
    gemm64<1><<<g256, blk, 0, stream>>>(x, prelin_w, nullptr, nullptr, prelin_b, hA,
                                        N_NODES, HID, DIM_IN);
    // conv1
    agg_kernel<<<agrid, ablk, 0, stream>>>(hA, srcs, attrs, rowptr, c1_we, c1_be, AGG);
    gemm64<1><<<g256, blk, 0, stream>>>(AGG, c1_wl, hA, c1_wr, c1_bl, hB, N_NODES, HID, HID);
    // hh1
    gemm64<2><<<g256, blk, 0, stream>>>(hB, hh1_w, nullptr, nullptr, hh1_b, hA, N_NODES, HID, HID);
    // conv2
    agg_kernel<<<agrid, ablk, 0, stream>>>(hA, srcs, attrs, rowptr, c2_we, c2_be, AGG);
    gemm64<1><<<g256, blk, 0, stream>>>(AGG, c2_wl, hA, c2_wr, c2_bl, hB, N_NODES, HID, HID);
    // hh2
    gemm64<2><<<g256, blk, 0, stream>>>(hB, hh2_w, nullptr, nullptr, hh2_b, hA, N_NODES, HID, HID);
    // conv3 (HID -> OUT)
    agg_kernel<<<agrid, ablk, 0, stream>>>(hA, srcs, attrs, rowptr, c3_we, c3_be, AGG);
    gemm64<1><<<g128, blk, 0, stream>>>(AGG, c3_wl, hA, c3_wr, c3_bl, hB, N_NODES, OUT_D, HID);
    // oo
    gemm64<2><<<g128, blk, 0, stream>>>(hB, oo_w, nullptr, nullptr, oo_b, hA, N_NODES, OUT_D, OUT_D);

    // global mean pool + head
    count_kernel<<<(N_NODES + 255) / 256, 256, 0, stream>>>(batch, gcnt, N_NODES);
    pool_kernel<<<80, 128, 0, stream>>>(hA, batch, gsum);
    pooled_mm<<<NG, 256, 0, stream>>>(gsum, gcnt, oh_w, oh_b, t2);
    finalize_kernel<<<1, 256, 0, stream>>>(t2, bn_g, bn_b, h1_w, h1_b, out);
}

// Round 10
// 547.023 us; speedup vs baseline: 1.4107x; 1.1420x over previous
//
#include <hip/hip_runtime.h>

#define N_NODES 10000
#define N_EDGES 320000
#define DIM_IN 128
#define HID 256
#define OUT_D 128
#define NG 64

// ---------------------------------------------------------------- bf16 utils

__device__ __forceinline__ float bf2f(unsigned short u) {
    union { unsigned int i; float f; } v;
    v.i = ((unsigned int)u) << 16;
    return v.f;
}
__device__ __forceinline__ unsigned short f2bf(float f) {
    union { float f; unsigned int i; } v;
    v.f = f;
    unsigned int b = v.i + 0x7FFFu + ((v.i >> 16) & 1u);   // RNE
    return (unsigned short)(b >> 16);
}

// ---------------------------------------------------------------- utilities

__global__ __launch_bounds__(256) void zero_kernel(unsigned int* __restrict__ p, int n) {
    int i = blockIdx.x * 256 + threadIdx.x;
    if (i < n) p[i] = 0u;
}

// ---------------------------------------------------------------- CSR build

__global__ __launch_bounds__(256) void hist_kernel(const int* __restrict__ dst,
                                                   int* __restrict__ cnt, int n) {
    int i = blockIdx.x * 256 + threadIdx.x;
    if (i < n) atomicAdd(&cnt[dst[i]], 1);
}

__global__ __launch_bounds__(1024) void scan_kernel(const int* __restrict__ cnt,
                                                    int* __restrict__ rowptr, int n) {
    __shared__ int lds[1024];
    int t = threadIdx.x;
    const int CH = 10;
    int base = t * CH;
    int loc[CH];
    int s = 0;
#pragma unroll
    for (int i = 0; i < CH; ++i) {
        int v = (base + i < n) ? cnt[base + i] : 0;
        loc[i] = s;
        s += v;
    }
    lds[t] = s;
    __syncthreads();
    for (int off = 1; off < 1024; off <<= 1) {
        int v = (t >= off) ? lds[t - off] : 0;
        __syncthreads();
        lds[t] += v;
        __syncthreads();
    }
    int excl = lds[t] - s;
#pragma unroll
    for (int i = 0; i < CH; ++i)
        if (base + i < n) rowptr[base + i] = excl + loc[i];
    if (t == 1023) rowptr[n] = lds[1023];
}

__global__ __launch_bounds__(256) void scatter_kernel(const int* __restrict__ src,
                                                      const int* __restrict__ dst,
                                                      const float* __restrict__ eattr,
                                                      const int* __restrict__ rowptr,
                                                      int* __restrict__ fill,
                                                      int* __restrict__ srcs,
                                                      float* __restrict__ attrs, int n) {
    int i = blockIdx.x * 256 + threadIdx.x;
    if (i < n) {
        int d = dst[i];
        int pos = rowptr[d] + atomicAdd(&fill[d], 1);
        srcs[pos] = src[i];
        attrs[pos] = eattr[i];
    }
}

// ------------------------------------------------- SAGE aggregate: bf16 table

__global__ __launch_bounds__(256) void agg16_kernel(const unsigned short* __restrict__ h16,
                                                    const int* __restrict__ srcs,
                                                    const float* __restrict__ attrs,
                                                    const int* __restrict__ rowptr,
                                                    const float* __restrict__ we,
                                                    const float* __restrict__ be,
                                                    float* __restrict__ agg) {
    int n = (blockIdx.x << 2) + (threadIdx.x >> 6);
    int c4 = (threadIdx.x & 63) << 2;
    float4 wv = *(const float4*)&we[c4];
    float4 bv = *(const float4*)&be[c4];
    int p0 = rowptr[n], p1 = rowptr[n + 1];
    float4 acc0 = make_float4(0.f, 0.f, 0.f, 0.f);
    float4 acc1 = make_float4(0.f, 0.f, 0.f, 0.f);
    int p = p0;
    for (; p + 4 <= p1; p += 4) {
        int s0 = srcs[p], s1 = srcs[p + 1], s2 = srcs[p + 2], s3 = srcs[p + 3];
        float e0 = attrs[p], e1 = attrs[p + 1], e2 = attrs[p + 2], e3 = attrs[p + 3];
        ushort4 u0 = *(const ushort4*)&h16[(size_t)s0 * HID + c4];
        ushort4 u1 = *(const ushort4*)&h16[(size_t)s1 * HID + c4];
        ushort4 u2 = *(const ushort4*)&h16[(size_t)s2 * HID + c4];
        ushort4 u3 = *(const ushort4*)&h16[(size_t)s3 * HID + c4];
        acc0.x += fmaxf(bf2f(u0.x) + e0 * wv.x + bv.x, 0.f);
        acc0.y += fmaxf(bf2f(u0.y) + e0 * wv.y + bv.y, 0.f);
        acc0.z += fmaxf(bf2f(u0.z) + e0 * wv.z + bv.z, 0.f);
        acc0.w += fmaxf(bf2f(u0.w) + e0 * wv.w + bv.w, 0.f);
        acc1.x += fmaxf(bf2f(u1.x) + e1 * wv.x + bv.x, 0.f);
        acc1.y += fmaxf(bf2f(u1.y) + e1 * wv.y + bv.y, 0.f);
        acc1.z += fmaxf(bf2f(u1.z) + e1 * wv.z + bv.z, 0.f);
        acc1.w += fmaxf(bf2f(u1.w) + e1 * wv.w + bv.w, 0.f);
        acc0.x += fmaxf(bf2f(u2.x) + e2 * wv.x + bv.x, 0.f);
        acc0.y += fmaxf(bf2f(u2.y) + e2 * wv.y + bv.y, 0.f);
        acc0.z += fmaxf(bf2f(u2.z) + e2 * wv.z + bv.z, 0.f);
        acc0.w += fmaxf(bf2f(u2.w) + e2 * wv.w + bv.w, 0.f);
        acc1.x += fmaxf(bf2f(u3.x) + e3 * wv.x + bv.x, 0.f);
        acc1.y += fmaxf(bf2f(u3.y) + e3 * wv.y + bv.y, 0.f);
        acc1.z += fmaxf(bf2f(u3.z) + e3 * wv.z + bv.z, 0.f);
        acc1.w += fmaxf(bf2f(u3.w) + e3 * wv.w + bv.w, 0.f);
    }
    for (; p < p1; ++p) {
        int s0 = srcs[p];
        float e0 = attrs[p];
        ushort4 u0 = *(const ushort4*)&h16[(size_t)s0 * HID + c4];
        acc0.x += fmaxf(bf2f(u0.x) + e0 * wv.x + bv.x, 0.f);
        acc0.y += fmaxf(bf2f(u0.y) + e0 * wv.y + bv.y, 0.f);
        acc0.z += fmaxf(bf2f(u0.z) + e0 * wv.z + bv.z, 0.f);
        acc0.w += fmaxf(bf2f(u0.w) + e0 * wv.w + bv.w, 0.f);
    }
    int deg = p1 - p0;
    float inv = 1.f / (float)(deg > 0 ? deg : 1);
    float4 o;
    o.x = (acc0.x + acc1.x) * inv;
    o.y = (acc0.y + acc1.y) * inv;
    o.z = (acc0.z + acc1.z) * inv;
    o.w = (acc0.w + acc1.w) * inv;
    *(float4*)&agg[(size_t)n * HID + c4] = o;
}

// ------------------------------------------------- SAGE aggregate: fp32 table
// (fallback path — exact round-6-passed kernel)

__global__ __launch_bounds__(256) void agg32_kernel(const float* __restrict__ h,
                                                    const int* __restrict__ srcs,
                                                    const float* __restrict__ attrs,
                                                    const int* __restrict__ rowptr,
                                                    const float* __restrict__ we,
                                                    const float* __restrict__ be,
                                                    float* __restrict__ agg) {
    int n = (blockIdx.x << 2) + (threadIdx.x >> 6);
    int c4 = (threadIdx.x & 63) << 2;
    float4 wv = *(const float4*)&we[c4];
    float4 bv = *(const float4*)&be[c4];
    int p0 = rowptr[n], p1 = rowptr[n + 1];
    float4 a0 = make_float4(0.f, 0.f, 0.f, 0.f);
    float4 a1 = make_float4(0.f, 0.f, 0.f, 0.f);
    int p = p0;
    for (; p + 2 <= p1; p += 2) {
        int s0 = srcs[p], s1 = srcs[p + 1];
        float e0 = attrs[p], e1 = attrs[p + 1];
        float4 h0 = *(const float4*)&h[(size_t)s0 * HID + c4];
        float4 h1 = *(const float4*)&h[(size_t)s1 * HID + c4];
        a0.x += fmaxf(h0.x + e0 * wv.x + bv.x, 0.f);
        a0.y += fmaxf(h0.y + e0 * wv.y + bv.y, 0.f);
        a0.z += fmaxf(h0.z + e0 * wv.z + bv.z, 0.f);
        a0.w += fmaxf(h0.w + e0 * wv.w + bv.w, 0.f);
        a1.x += fmaxf(h1.x + e1 * wv.x + bv.x, 0.f);
        a1.y += fmaxf(h1.y + e1 * wv.y + bv.y, 0.f);
        a1.z += fmaxf(h1.z + e1 * wv.z + bv.z, 0.f);
        a1.w += fmaxf(h1.w + e1 * wv.w + bv.w, 0.f);
    }
    if (p < p1) {
        int s0 = srcs[p];
        float e0 = attrs[p];
        float4 h0 = *(const float4*)&h[(size_t)s0 * HID + c4];
        a0.x += fmaxf(h0.x + e0 * wv.x + bv.x, 0.f);
        a0.y += fmaxf(h0.y + e0 * wv.y + bv.y, 0.f);
        a0.z += fmaxf(h0.z + e0 * wv.z + bv.z, 0.f);
        a0.w += fmaxf(h0.w + e0 * wv.w + bv.w, 0.f);
    }
    int deg = p1 - p0;
    float inv = 1.f / (float)(deg > 0 ? deg : 1);
    float4 o;
    o.x = (a0.x + a1.x) * inv;
    o.y = (a0.y + a1.y) * inv;
    o.z = (a0.z + a1.z) * inv;
    o.w = (a0.w + a1.w) * inv;
    *(float4*)&agg[(size_t)n * HID + c4] = o;
}

// ---------------------------------------------------------------- GEMM (fused)
// C[M,N] = act( A@B (+ A2@B2) + bias ), optional bf16 dual-write.
// 64x64 tile, 256 thr, 4x4/thread, BK=32, reg prefetch, XCD-bijective swizzle.

__device__ __forceinline__ float4 ldg4g(const float* __restrict__ p, int r, int c,
                                        int M, int ld) {
    if (r < M) return *(const float4*)(p + (size_t)r * ld + c);
    return make_float4(0.f, 0.f, 0.f, 0.f);
}

template <int ACT>  // 1 = relu, 2 = leaky(0.01)
__global__ __launch_bounds__(256) void gemm64f(const float* __restrict__ A,
                                               const float* __restrict__ B,
                                               const float* __restrict__ A2,
                                               const float* __restrict__ B2,
                                               const float* __restrict__ bias,
                                               float* __restrict__ C,
                                               unsigned short* __restrict__ Cb,
                                               int M, int N, int K) {
    __shared__ float As[32][72];
    __shared__ float Bs[32][64];
    int tid = threadIdx.x;
    int tc = tid & 15, tr = tid >> 4;

    int gx = gridDim.x, nwg = gx * gridDim.y;
    int orig = blockIdx.y * gx + blockIdx.x;
    int q = nwg >> 3, r = nwg & 7;
    int xcd = orig & 7, loc = orig >> 3;
    int t = (xcd < r) ? (xcd * (q + 1) + loc) : (r * (q + 1) + (xcd - r) * q + loc);
    int row0 = (t / gx) << 6, col0 = (t % gx) << 6;

    int arow = tid >> 2;
    int ak8 = (tid & 3) << 3;
    int bk = tid >> 4;
    int bc = (tid & 15) << 2;

    float acc[4][4] = {};
    const float* APs[2] = {A, A2 ? A2 : A};
    const float* BPs[2] = {B, B2 ? B2 : B};
    int nt = K >> 5;
    int tnt = (A2 != nullptr) ? (nt << 1) : nt;

    float4 a0 = ldg4g(APs[0], row0 + arow, ak8, M, K);
    float4 a1 = ldg4g(APs[0], row0 + arow, ak8 + 4, M, K);
    float4 b0 = *(const float4*)&BPs[0][(size_t)bk * N + col0 + bc];
    float4 b1 = *(const float4*)&BPs[0][(size_t)(bk + 16) * N + col0 + bc];

    for (int tt = 0; tt < tnt; ++tt) {
        __syncthreads();
        As[ak8 + 0][arow] = a0.x; As[ak8 + 1][arow] = a0.y;
        As[ak8 + 2][arow] = a0.z; As[ak8 + 3][arow] = a0.w;
        As[ak8 + 4][arow] = a1.x; As[ak8 + 5][arow] = a1.y;
        As[ak8 + 6][arow] = a1.z; As[ak8 + 7][arow] = a1.w;
        *(float4*)&Bs[bk][bc] = b0;
        *(float4*)&Bs[bk + 16][bc] = b1;
        __syncthreads();
        if (tt + 1 < tnt) {
            int tp = tt + 1;
            int ps = (tp >= nt) ? 1 : 0;
            int k0 = (tp - (ps ? nt : 0)) << 5;
            const float* Ax = APs[ps];
            const float* Bx = BPs[ps];
            a0 = ldg4g(Ax, row0 + arow, k0 + ak8, M, K);
            a1 = ldg4g(Ax, row0 + arow, k0 + ak8 + 4, M, K);
            b0 = *(const float4*)&Bx[(size_t)(k0 + bk) * N + col0 + bc];
            b1 = *(const float4*)&Bx[(size_t)(k0 + bk + 16) * N + col0 + bc];
        }
#pragma unroll
        for (int k = 0; k < 32; ++k) {
            float4 av = *(const float4*)&As[k][tr << 2];
            float4 bv = *(const float4*)&Bs[k][tc << 2];
            acc[0][0] += av.x * bv.x; acc[0][1] += av.x * bv.y;
            acc[0][2] += av.x * bv.z; acc[0][3] += av.x * bv.w;
            acc[1][0] += av.y * bv.x; acc[1][1] += av.y * bv.y;
            acc[1][2] += av.y * bv.z; acc[1][3] += av.y * bv.w;
            acc[2][0] += av.z * bv.x; acc[2][1] += av.z * bv.y;
            acc[2][2] += av.z * bv.z; acc[2][3] += av.z * bv.w;
            acc[3][0] += av.w * bv.x; acc[3][1] += av.w * bv.y;
            acc[3][2] += av.w * bv.z; acc[3][3] += av.w * bv.w;
        }
    }

    float4 bb = *(const float4*)&bias[col0 + (tc << 2)];
#pragma unroll
    for (int i = 0; i < 4; ++i) {
        int rr = row0 + (tr << 2) + i;
        if (rr < M) {
            float4 o;
            o.x = acc[i][0] + bb.x; o.y = acc[i][1] + bb.y;
            o.z = acc[i][2] + bb.z; o.w = acc[i][3] + bb.w;
            if (ACT == 1) {
                o.x = fmaxf(o.x, 0.f); o.y = fmaxf(o.y, 0.f);
                o.z = fmaxf(o.z, 0.f); o.w = fmaxf(o.w, 0.f);
            } else {
                o.x = (o.x >= 0.f) ? o.x : 0.01f * o.x;
                o.y = (o.y >= 0.f) ? o.y : 0.01f * o.y;
                o.z = (o.z >= 0.f) ? o.z : 0.01f * o.z;
                o.w = (o.w >= 0.f) ? o.w : 0.01f * o.w;
            }
            *(float4*)&C[(size_t)rr * N + col0 + (tc << 2)] = o;
            if (Cb) {
                ushort4 ub;
                ub.x = f2bf(o.x); ub.y = f2bf(o.y);
                ub.z = f2bf(o.z); ub.w = f2bf(o.w);
                *(ushort4*)&Cb[(size_t)rr * N + col0 + (tc << 2)] = ub;
            }
        }
    }
}

// ------------------------------------------------- GEMM (split, gridDim.z=2)
// z=0: C0 = A@B ; z=1: C1 = A2@B2.  No bias/act. 2x blocks in flight.

__global__ __launch_bounds__(256) void gemm64p(const float* __restrict__ A,
                                               const float* __restrict__ B,
                                               const float* __restrict__ A2,
                                               const float* __restrict__ B2,
                                               float* __restrict__ C0,
                                               float* __restrict__ C1,
                                               int M, int N, int lda, int Kz) {
    __shared__ float As[32][72];
    __shared__ float Bs[32][64];
    int tid = threadIdx.x;
    int tc = tid & 15, tr = tid >> 4;

    const float* Ap = (blockIdx.z == 0) ? A : A2;
    const float* Bp = (blockIdx.z == 0) ? B : B2;
    float* Cp = (blockIdx.z == 0) ? C0 : C1;

    int gx = gridDim.x, nwg = gx * gridDim.y;
    int orig = blockIdx.y * gx + blockIdx.x;
    int q = nwg >> 3, r = nwg & 7;
    int xcd = orig & 7, loc = orig >> 3;
    int t = (xcd < r) ? (xcd * (q + 1) + loc) : (r * (q + 1) + (xcd - r) * q + loc);
    int row0 = (t / gx) << 6, col0 = (t % gx) << 6;

    int arow = tid >> 2;
    int ak8 = (tid & 3) << 3;
    int bk = tid >> 4;
    int bc = (tid & 15) << 2;

    float acc[4][4] = {};
    int nt = Kz >> 5;

    float4 a0 = ldg4g(Ap, row0 + arow, ak8, M, lda);
    float4 a1 = ldg4g(Ap, row0 + arow, ak8 + 4, M, lda);
    float4 b0 = *(const float4*)&Bp[(size_t)bk * N + col0 + bc];
    float4 b1 = *(const float4*)&Bp[(size_t)(bk + 16) * N + col0 + bc];

    for (int tt = 0; tt < nt; ++tt) {
        __syncthreads();
        As[ak8 + 0][arow] = a0.x; As[ak8 + 1][arow] = a0.y;
        As[ak8 + 2][arow] = a0.z; As[ak8 + 3][arow] = a0.w;
        As[ak8 + 4][arow] = a1.x; As[ak8 + 5][arow] = a1.y;
        As[ak8 + 6][arow] = a1.z; As[ak8 + 7][arow] = a1.w;
        *(float4*)&Bs[bk][bc] = b0;
        *(float4*)&Bs[bk + 16][bc] = b1;
        __syncthreads();
        if (tt + 1 < nt) {
            int k0 = (tt + 1) << 5;
            a0 = ldg4g(Ap, row0 + arow, k0 + ak8, M, lda);
            a1 = ldg4g(Ap, row0 + arow, k0 + ak8 + 4, M, lda);
            b0 = *(const float4*)&Bp[(size_t)(k0 + bk) * N + col0 + bc];
            b1 = *(const float4*)&Bp[(size_t)(k0 + bk + 16) * N + col0 + bc];
        }
#pragma unroll
        for (int k = 0; k < 32; ++k) {
            float4 av = *(const float4*)&As[k][tr << 2];
            float4 bv = *(const float4*)&Bs[k][tc << 2];
            acc[0][0] += av.x * bv.x; acc[0][1] += av.x * bv.y;
            acc[0][2] += av.x * bv.z; acc[0][3] += av.x * bv.w;
            acc[1][0] += av.y * bv.x; acc[1][1] += av.y * bv.y;
            acc[1][2] += av.y * bv.z; acc[1][3] += av.y * bv.w;
            acc[2][0] += av.z * bv.x; acc[2][1] += av.z * bv.y;
            acc[2][2] += av.z * bv.z; acc[2][3] += av.z * bv.w;
            acc[3][0] += av.w * bv.x; acc[3][1] += av.w * bv.y;
            acc[3][2] += av.w * bv.z; acc[3][3] += av.w * bv.w;
        }
    }

#pragma unroll
    for (int i = 0; i < 4; ++i) {
        int rr = row0 + (tr << 2) + i;
        if (rr < M) {
            float4 o;
            o.x = acc[i][0]; o.y = acc[i][1]; o.z = acc[i][2]; o.w = acc[i][3];
            *(float4*)&Cp[(size_t)rr * N + col0 + (tc << 2)] = o;
        }
    }
}

// C = act(P0 + P1 + bias); optional bf16 dual-write. C may alias P0.
template <int ACT>
__global__ __launch_bounds__(256) void addact_kernel(const float* __restrict__ P0,
                                                     const float* __restrict__ P1,
                                                     const float* __restrict__ bias,
                                                     float* __restrict__ C,
                                                     unsigned short* __restrict__ Cb,
                                                     int nmask) {
    int i4 = (blockIdx.x * 256 + threadIdx.x) << 2;
    float4 p0 = *(const float4*)&P0[i4];
    float4 p1 = *(const float4*)&P1[i4];
    float4 bb = *(const float4*)&bias[i4 & nmask];
    float4 o;
    o.x = p0.x + p1.x + bb.x;
    o.y = p0.y + p1.y + bb.y;
    o.z = p0.z + p1.z + bb.z;
    o.w = p0.w + p1.w + bb.w;
    if (ACT == 1) {
        o.x = fmaxf(o.x, 0.f); o.y = fmaxf(o.y, 0.f);
        o.z = fmaxf(o.z, 0.f); o.w = fmaxf(o.w, 0.f);
    } else {
        o.x = (o.x >= 0.f) ? o.x : 0.01f * o.x;
        o.y = (o.y >= 0.f) ? o.y : 0.01f * o.y;
        o.z = (o.z >= 0.f) ? o.z : 0.01f * o.z;
        o.w = (o.w >= 0.f) ? o.w : 0.01f * o.w;
    }
    *(float4*)&C[i4] = o;
    if (Cb) {
        ushort4 ub;
        ub.x = f2bf(o.x); ub.y = f2bf(o.y); ub.z = f2bf(o.z); ub.w = f2bf(o.w);
        *(ushort4*)&Cb[i4] = ub;
    }
}

// ---------------------------------------------------------------- pooling

__global__ __launch_bounds__(256) void count_kernel(const int* __restrict__ batch,
                                                    int* __restrict__ gcnt, int n) {
    int i = blockIdx.x * 256 + threadIdx.x;
    if (i < n) atomicAdd(&gcnt[batch[i]], 1);
}

__global__ __launch_bounds__(128) void pool_kernel(const float* __restrict__ h,
                                                   const int* __restrict__ batch,
                                                   float* __restrict__ gsum) {
    int c = threadIdx.x;
    int r0 = blockIdx.x * 125, r1 = r0 + 125;
    float acc = 0.f;
    int cur = batch[r0];
    for (int r = r0; r < r1; ++r) {
        int b = batch[r];
        if (b != cur) {
            atomicAdd(&gsum[cur * OUT_D + c], acc);
            acc = 0.f;
            cur = b;
        }
        acc += h[(size_t)r * OUT_D + c];
    }
    atomicAdd(&gsum[cur * OUT_D + c], acc);
}

__global__ __launch_bounds__(256) void pooled_mm(const float* __restrict__ gsum,
                                                 const int* __restrict__ gcnt,
                                                 const float* __restrict__ ohw,
                                                 const float* __restrict__ ohb,
                                                 float* __restrict__ t2) {
    __shared__ float gm[OUT_D];
    int r = blockIdx.x;
    int c = threadIdx.x;
    if (c < OUT_D) {
        int ct = gcnt[r];
        gm[c] = gsum[r * OUT_D + c] / (float)(ct > 0 ? ct : 1);
    }
    __syncthreads();
    float acc = ohb[c];
    for (int k = 0; k < OUT_D; ++k) acc += gm[k] * ohw[k * HID + c];
    t2[r * HID + c] = acc;
}

__global__ __launch_bounds__(256) void finalize_kernel(const float* __restrict__ t2,
                                                       const float* __restrict__ gamma,
                                                       const float* __restrict__ beta,
                                                       const float* __restrict__ h1w,
                                                       const float* __restrict__ h1b,
                                                       float* __restrict__ out) {
    __shared__ float tl[NG][HID];
    int c = threadIdx.x;
    float mean = 0.f;
    for (int r = 0; r < NG; ++r) mean += t2[r * HID + c];
    mean *= (1.f / (float)NG);
    float var = 0.f;
    for (int r = 0; r < NG; ++r) {
        float d = t2[r * HID + c] - mean;
        var += d * d;
    }
    var *= (1.f / (float)NG);
    float sc = gamma[c] / sqrtf(var + 1e-5f);
    float sh = beta[c] - mean * sc;
    for (int r = 0; r < NG; ++r) {
        float v = t2[r * HID + c] * sc + sh;
        tl[r][c] = (v >= 0.f) ? v : 0.01f * v;
    }
    __syncthreads();
    int wid = c >> 6, lane = c & 63;
    float4 wv = *(const float4*)&h1w[lane << 2];
    float b0 = h1b[0];
    for (int row = wid; row < NG; row += 4) {
        float4 v = *(const float4*)&tl[row][lane << 2];
        float s = v.x * wv.x + v.y * wv.y + v.z * wv.z + v.w * wv.w;
#pragma unroll
        for (int off = 32; off >= 1; off >>= 1) s += __shfl_xor(s, off);
        if (lane == 0) out[row] = fmaxf(s + b0, 0.f);
    }
}

// ---------------------------------------------------------------- driver

extern "C" void kernel_launch(void* const* d_in, const int* in_sizes, int n_in,
                              void* d_out, int out_size, void* d_ws, size_t ws_size,
                              hipStream_t stream) {
    const float* x        = (const float*)d_in[0];
    const int*   ei       = (const int*)d_in[1];
    const float* eattr    = (const float*)d_in[2];
    const int*   batch    = (const int*)d_in[3];
    const float* prelin_w = (const float*)d_in[4];
    const float* prelin_b = (const float*)d_in[5];
    const float* c1_wl = (const float*)d_in[6],  *c1_bl = (const float*)d_in[7];
    const float* c1_wr = (const float*)d_in[8],  *c1_we = (const float*)d_in[9];
    const float* c1_be = (const float*)d_in[10];
    const float* c2_wl = (const float*)d_in[11], *c2_bl = (const float*)d_in[12];
    const float* c2_wr = (const float*)d_in[13], *c2_we = (const float*)d_in[14];
    const float* c2_be = (const float*)d_in[15];
    const float* c3_wl = (const float*)d_in[16], *c3_bl = (const float*)d_in[17];
    const float* c3_wr = (const float*)d_in[18], *c3_we = (const float*)d_in[19];
    const float* c3_be = (const float*)d_in[20];
    const float* hh1_w = (const float*)d_in[21], *hh1_b = (const float*)d_in[22];
    const float* hh2_w = (const float*)d_in[23], *hh2_b = (const float*)d_in[24];
    const float* oo_w  = (const float*)d_in[25], *oo_b  = (const float*)d_in[26];
    const float* oh_w  = (const float*)d_in[27], *oh_b  = (const float*)d_in[28];
    const float* h1_w  = (const float*)d_in[29], *h1_b  = (const float*)d_in[30];
    const float* bn_g  = (const float*)d_in[31], *bn_b  = (const float*)d_in[32];
    float* out = (float*)d_out;

    const int* srcp = ei;
    const int* dstp = ei + N_EDGES;

    // big layout needs 48,858,564 bytes; fallback needs 33,498,564 (proven).
    bool big = (ws_size >= 48900000ULL);

    float* ws = (float*)d_ws;
    float* hA  = ws;                                 // [10000,256]
    float* hB  = hA + 2560000;                       // [10000,256]
    float* AGG = hB + 2560000;                       // [10000,256]
    float* P1  = nullptr;
    unsigned short* h16 = nullptr;
    float* tail = AGG + 2560000;
    if (big) {
        P1  = tail;                                  // [10000,256]
        h16 = (unsigned short*)(P1 + 2560000);       // [10000,256] bf16
        tail = P1 + 2560000 + 1280000;
    }
    float* t2    = tail;                             // [64,256]
    float* gsum  = t2 + NG * HID;                    // [64,128]
    int*   gcnt  = (int*)(gsum + NG * OUT_D);        // [64]
    int*   rowptr = gcnt + NG;                       // [10001]
    int*   cnt   = rowptr + (N_NODES + 1);           // [10000]
    int*   fill  = cnt + N_NODES;                    // [10000]
    int*   srcs  = fill + N_NODES;                   // [320000]
    float* attrs = (float*)(srcs + N_EDGES);         // [320000]

    zero_kernel<<<(2 * N_NODES + 255) / 256, 256, 0, stream>>>((unsigned int*)cnt, 2 * N_NODES);
    zero_kernel<<<(NG * OUT_D + NG + 255) / 256, 256, 0, stream>>>((unsigned int*)gsum, NG * OUT_D + NG);

    hist_kernel<<<(N_EDGES + 255) / 256, 256, 0, stream>>>(dstp, cnt, N_EDGES);
    scan_kernel<<<1, 1024, 0, stream>>>(cnt, rowptr, N_NODES);
    scatter_kernel<<<(N_EDGES + 255) / 256, 256, 0, stream>>>(srcp, dstp, eattr, rowptr,
                                                              fill, srcs, attrs, N_EDGES);

    dim3 blk(256);
    dim3 g256(HID / 64, (N_NODES + 63) / 64);
    dim3 g128(OUT_D / 64, (N_NODES + 63) / 64);
    int agrid = N_NODES / 4;

    if (big) {
        dim3 gp256(HID / 64, (N_NODES + 63) / 64, 2);
        dim3 gp128(OUT_D / 64, (N_NODES + 63) / 64, 2);
        int ea256 = N_NODES * HID / 1024;
        int ea128 = N_NODES * OUT_D / 1024;

        gemm64f<1><<<g256, blk, 0, stream>>>(x, prelin_w, nullptr, nullptr, prelin_b,
                                             hA, h16, N_NODES, HID, DIM_IN);
        // conv1
        agg16_kernel<<<agrid, blk, 0, stream>>>(h16, srcs, attrs, rowptr, c1_we, c1_be, AGG);
        gemm64p<<<gp256, blk, 0, stream>>>(AGG, c1_wl, hA, c1_wr, hB, P1,
                                           N_NODES, HID, HID, HID);
        addact_kernel<1><<<ea256, blk, 0, stream>>>(hB, P1, c1_bl, hB, nullptr, HID - 1);
        // hh1 (split-K 128+128)
        gemm64p<<<gp256, blk, 0, stream>>>(hB, hh1_w, hB + 128, hh1_w + 128 * HID, hA, P1,
                                           N_NODES, HID, HID, 128);
        addact_kernel<2><<<ea256, blk, 0, stream>>>(hA, P1, hh1_b, hA, h16, HID - 1);
        // conv2
        agg16_kernel<<<agrid, blk, 0, stream>>>(h16, srcs, attrs, rowptr, c2_we, c2_be, AGG);
        gemm64p<<<gp256, blk, 0, stream>>>(AGG, c2_wl, hA, c2_wr, hB, P1,
                                           N_NODES, HID, HID, HID);
        addact_kernel<1><<<ea256, blk, 0, stream>>>(hB, P1, c2_bl, hB, nullptr, HID - 1);
        // hh2
        gemm64p<<<gp256, blk, 0, stream>>>(hB, hh2_w, hB + 128, hh2_w + 128 * HID, hA, P1,
                                           N_NODES, HID, HID, 128);
        addact_kernel<2><<<ea256, blk, 0, stream>>>(hA, P1, hh2_b, hA, h16, HID - 1);
        // conv3 (HID -> OUT)
        agg16_kernel<<<agrid, blk, 0, stream>>>(h16, srcs, attrs, rowptr, c3_we, c3_be, AGG);
        gemm64p<<<gp128, blk, 0, stream>>>(AGG, c3_wl, hA, c3_wr, hB, P1,
                                           N_NODES, OUT_D, HID, HID);
        addact_kernel<1><<<ea128, blk, 0, stream>>>(hB, P1, c3_bl, hB, nullptr, OUT_D - 1);
        // oo
        gemm64f<2><<<g128, blk, 0, stream>>>(hB, oo_w, nullptr, nullptr, oo_b,
                                             hA, nullptr, N_NODES, OUT_D, OUT_D);
    } else {
        // exact round-6-passed pipeline (fp32 throughout, fused two-pass convs)
        gemm64f<1><<<g256, blk, 0, stream>>>(x, prelin_w, nullptr, nullptr, prelin_b,
                                             hA, nullptr, N_NODES, HID, DIM_IN);
        agg32_kernel<<<agrid, blk, 0, stream>>>(hA, srcs, attrs, rowptr, c1_we, c1_be, AGG);
        gemm64f<1><<<g256, blk, 0, stream>>>(AGG, c1_wl, hA, c1_wr, c1_bl,
                                             hB, nullptr, N_NODES, HID, HID);
        gemm64f<2><<<g256, blk, 0, stream>>>(hB, hh1_w, nullptr, nullptr, hh1_b,
                                             hA, nullptr, N_NODES, HID, HID);
        agg32_kernel<<<agrid, blk, 0, stream>>>(hA, srcs, attrs, rowptr, c2_we, c2_be, AGG);
        gemm64f<1><<<g256, blk, 0, stream>>>(AGG, c2_wl, hA, c2_wr, c2_bl,
                                             hB, nullptr, N_NODES, HID, HID);
        gemm64f<2><<<g256, blk, 0, stream>>>(hB, hh2_w, nullptr, nullptr, hh2_b,
                                             hA, nullptr, N_NODES, HID, HID);
        agg32_kernel<<<agrid, blk, 0, stream>>>(hA, srcs, attrs, rowptr, c3_we, c3_be, AGG);
        gemm64f<1><<<g128, blk, 0, stream>>>(AGG, c3_wl, hA, c3_wr, c3_bl,
                                             hB, nullptr, N_NODES, OUT_D, HID);
        gemm64f<2><<<g128, blk, 0, stream>>>(hB, oo_w, nullptr, nullptr, oo_b,
                                             hA, nullptr, N_NODES, OUT_D, OUT_D);
    }

    count_kernel<<<(N_NODES + 255) / 256, 256, 0, stream>>>(batch, gcnt, N_NODES);
    pool_kernel<<<80, 128, 0, stream>>>(hA, batch, gsum);
    pooled_mm<<<NG, 256, 0, stream>>>(gsum, gcnt, oh_w, oh_b, t2);
    finalize_kernel<<<1, 256, 0, stream>>>(t2, bn_g, bn_b, h1_w, h1_b, out);
}

// Round 13
// 424.556 us; speedup vs baseline: 1.8176x; 1.2885x over previous
//
#include <hip/hip_runtime.h>

#define N_NODES 10000
#define N_EDGES 320000
#define DIM_IN 128
#define HID 256
#define OUT_D 128
#define NG 64

typedef short bf16x8 __attribute__((ext_vector_type(8)));
typedef float f32x4 __attribute__((ext_vector_type(4)));

// ---------------------------------------------------------------- bf16 utils

__device__ __forceinline__ float bf2f(unsigned short u) {
    union { unsigned int i; float f; } v;
    v.i = ((unsigned int)u) << 16;
    return v.f;
}
__device__ __forceinline__ unsigned short f2bf(float f) {
    union { float f; unsigned int i; } v;
    v.f = f;
    unsigned int b = v.i + 0x7FFFu + ((v.i >> 16) & 1u);   // RNE
    return (unsigned short)(b >> 16);
}

// ---------------------------------------------------------------- utilities

__global__ __launch_bounds__(256) void zero_kernel(unsigned int* __restrict__ p, int n) {
    int i = blockIdx.x * 256 + threadIdx.x;
    if (i < n) p[i] = 0u;
}

// weight pack: W[k][n] (f32) -> Wt_hi[n][k], Wt_lo[n][k] (double-bf16 split)
struct W10 {
    const float* w[10];
    unsigned short* oh[10];
    unsigned short* ol[10];
    int K[10];
    int N[10];
};
__global__ __launch_bounds__(256) void w2bt_kernel(W10 p) {
    int id = blockIdx.z;
    int K = p.K[id], N = p.N[id];
    int n = blockIdx.x * 16 + (threadIdx.x & 15);
    int k = blockIdx.y * 16 + (threadIdx.x >> 4);
    if (n < N && k < K) {
        float v = p.w[id][(size_t)k * N + n];
        unsigned short hi = f2bf(v);
        unsigned short lo = f2bf(v - bf2f(hi));
        p.oh[id][(size_t)n * K + k] = hi;
        p.ol[id][(size_t)n * K + k] = lo;
    }
}

// ---------------------------------------------------------------- CSR build

__global__ __launch_bounds__(256) void hist_kernel(const int* __restrict__ dst,
                                                   int* __restrict__ cnt, int n) {
    int i = blockIdx.x * 256 + threadIdx.x;
    if (i < n) atomicAdd(&cnt[dst[i]], 1);
}

__global__ __launch_bounds__(1024) void scan_kernel(const int* __restrict__ cnt,
                                                    int* __restrict__ rowptr, int n) {
    __shared__ int lds[1024];
    int t = threadIdx.x;
    const int CH = 10;
    int base = t * CH;
    int loc[CH];
    int s = 0;
#pragma unroll
    for (int i = 0; i < CH; ++i) {
        int v = (base + i < n) ? cnt[base + i] : 0;
        loc[i] = s;
        s += v;
    }
    lds[t] = s;
    __syncthreads();
    for (int off = 1; off < 1024; off <<= 1) {
        int v = (t >= off) ? lds[t - off] : 0;
        __syncthreads();
        lds[t] += v;
        __syncthreads();
    }
    int excl = lds[t] - s;
#pragma unroll
    for (int i = 0; i < CH; ++i)
        if (base + i < n) rowptr[base + i] = excl + loc[i];
    if (t == 1023) rowptr[n] = lds[1023];
}

__global__ __launch_bounds__(256) void scatter_kernel(const int* __restrict__ src,
                                                      const int* __restrict__ dst,
                                                      const float* __restrict__ eattr,
                                                      const int* __restrict__ rowptr,
                                                      int* __restrict__ fill,
                                                      int* __restrict__ srcs,
                                                      float* __restrict__ attrs, int n) {
    int i = blockIdx.x * 256 + threadIdx.x;
    if (i < n) {
        int d = dst[i];
        int pos = rowptr[d] + atomicAdd(&fill[d], 1);
        srcs[pos] = src[i];
        attrs[pos] = eattr[i];
    }
}

// batch is SORTED: per-group count = boundary difference via binary search.
__global__ __launch_bounds__(128) void gcount_kernel(const int* __restrict__ batch,
                                                     int* __restrict__ gcnt) {
    __shared__ int lb[NG + 1];
    int t = threadIdx.x;
    if (t <= NG) {
        int lo = 0, hi = N_NODES;
        while (lo < hi) {
            int mid = (lo + hi) >> 1;
            if (batch[mid] < t) lo = mid + 1; else hi = mid;
        }
        lb[t] = lo;
    }
    __syncthreads();
    if (t < NG) gcnt[t] = lb[t + 1] - lb[t];
}

// ------------------------------------------------- SAGE aggregate
// AGG[n][c] = mean_e relu(h16[src[e]][c] + attr[e]*We[c] + be[c])  (fp32 out)

__global__ __launch_bounds__(256) void agg16_kernel(const unsigned short* __restrict__ h16,
                                                    const int* __restrict__ srcs,
                                                    const float* __restrict__ attrs,
                                                    const int* __restrict__ rowptr,
                                                    const float* __restrict__ we,
                                                    const float* __restrict__ be,
                                                    float* __restrict__ agg) {
    int n = (blockIdx.x << 2) + (threadIdx.x >> 6);
    int c4 = (threadIdx.x & 63) << 2;
    float4 wv = *(const float4*)&we[c4];
    float4 bv = *(const float4*)&be[c4];
    int p0 = rowptr[n], p1 = rowptr[n + 1];
    float4 acc0 = make_float4(0.f, 0.f, 0.f, 0.f);
    float4 acc1 = make_float4(0.f, 0.f, 0.f, 0.f);
    int p = p0;
    for (; p + 4 <= p1; p += 4) {
        int s0 = srcs[p], s1 = srcs[p + 1], s2 = srcs[p + 2], s3 = srcs[p + 3];
        float e0 = attrs[p], e1 = attrs[p + 1], e2 = attrs[p + 2], e3 = attrs[p + 3];
        ushort4 u0 = *(const ushort4*)&h16[(size_t)s0 * HID + c4];
        ushort4 u1 = *(const ushort4*)&h16[(size_t)s1 * HID + c4];
        ushort4 u2 = *(const ushort4*)&h16[(size_t)s2 * HID + c4];
        ushort4 u3 = *(const ushort4*)&h16[(size_t)s3 * HID + c4];
        acc0.x += fmaxf(bf2f(u0.x) + e0 * wv.x + bv.x, 0.f);
        acc0.y += fmaxf(bf2f(u0.y) + e0 * wv.y + bv.y, 0.f);
        acc0.z += fmaxf(bf2f(u0.z) + e0 * wv.z + bv.z, 0.f);
        acc0.w += fmaxf(bf2f(u0.w) + e0 * wv.w + bv.w, 0.f);
        acc1.x += fmaxf(bf2f(u1.x) + e1 * wv.x + bv.x, 0.f);
        acc1.y += fmaxf(bf2f(u1.y) + e1 * wv.y + bv.y, 0.f);
        acc1.z += fmaxf(bf2f(u1.z) + e1 * wv.z + bv.z, 0.f);
        acc1.w += fmaxf(bf2f(u1.w) + e1 * wv.w + bv.w, 0.f);
        acc0.x += fmaxf(bf2f(u2.x) + e2 * wv.x + bv.x, 0.f);
        acc0.y += fmaxf(bf2f(u2.y) + e2 * wv.y + bv.y, 0.f);
        acc0.z += fmaxf(bf2f(u2.z) + e2 * wv.z + bv.z, 0.f);
        acc0.w += fmaxf(bf2f(u2.w) + e2 * wv.w + bv.w, 0.f);
        acc1.x += fmaxf(bf2f(u3.x) + e3 * wv.x + bv.x, 0.f);
        acc1.y += fmaxf(bf2f(u3.y) + e3 * wv.y + bv.y, 0.f);
        acc1.z += fmaxf(bf2f(u3.z) + e3 * wv.z + bv.z, 0.f);
        acc1.w += fmaxf(bf2f(u3.w) + e3 * wv.w + bv.w, 0.f);
    }
    for (; p < p1; ++p) {
        int s0 = srcs[p];
        float e0 = attrs[p];
        ushort4 u0 = *(const ushort4*)&h16[(size_t)s0 * HID + c4];
        acc0.x += fmaxf(bf2f(u0.x) + e0 * wv.x + bv.x, 0.f);
        acc0.y += fmaxf(bf2f(u0.y) + e0 * wv.y + bv.y, 0.f);
        acc0.z += fmaxf(bf2f(u0.z) + e0 * wv.z + bv.z, 0.f);
        acc0.w += fmaxf(bf2f(u0.w) + e0 * wv.w + bv.w, 0.f);
    }
    int deg = p1 - p0;
    float inv = 1.f / (float)(deg > 0 ? deg : 1);
    float4 o;
    o.x = (acc0.x + acc1.x) * inv;
    o.y = (acc0.y + acc1.y) * inv;
    o.z = (acc0.z + acc1.z) * inv;
    o.w = (acc0.w + acc1.w) * inv;
    *(float4*)&agg[(size_t)n * HID + c4] = o;
}

// ---------------------------------------------------------------- MFMA GEMM
// Double-bf16 (Markidis split): A fp32 -> (Ah,Al) in-register at staging;
// W pre-split (Wh,Wl).  acc += Ah*Wh + Al*Wh + Ah*Wl  (Al*Wl ~ eps^2 dropped).
// C[M,N] = act( A@W (+ A2@W2) + bias ).  256 thr = 4 waves; 64x64 tile; K-chunk
// 32; v_mfma_f32_16x16x32_bf16, fp32 accum.  C/D map col=lane&15,
// row=(lane>>4)*4+reg [HW-verified].  Epilogue: bias+act, f32 write + optional
// bf16 gather-table write.

template <int ACT>  // 1 = relu, 2 = leaky(0.01)
__global__ __launch_bounds__(256) void gemmx(const float* __restrict__ A,
                                             const unsigned short* __restrict__ Wh,
                                             const unsigned short* __restrict__ Wl,
                                             const float* __restrict__ A2,
                                             const unsigned short* __restrict__ W2h,
                                             const unsigned short* __restrict__ W2l,
                                             const float* __restrict__ bias,
                                             float* __restrict__ C,
                                             unsigned short* __restrict__ Cb,
                                             int M, int N, int K) {
    __shared__ unsigned short Ash[64][40];
    __shared__ unsigned short Asl[64][40];
    __shared__ unsigned short Bsh[64][40];
    __shared__ unsigned short Bsl[64][40];
    int tid = threadIdx.x;
    int w = tid >> 6, lane = tid & 63;

    // bijective XCD swizzle
    int gx = gridDim.x, nwg = gx * gridDim.y;
    int orig = blockIdx.y * gx + blockIdx.x;
    int q = nwg >> 3, r = nwg & 7;
    int xcd = orig & 7, loc = orig >> 3;
    int t = (xcd < r) ? (xcd * (q + 1) + loc) : (r * (q + 1) + (xcd - r) * q + loc);
    int row0 = (t / gx) << 6, col0 = (t % gx) << 6;

    int srow = tid >> 2;        // staging row 0..63
    int sk8 = (tid & 3) << 3;   // staging k offset 0,8,16,24

    f32x4 acc[4];
#pragma unroll
    for (int j = 0; j < 4; ++j) {
        acc[j][0] = 0.f; acc[j][1] = 0.f; acc[j][2] = 0.f; acc[j][3] = 0.f;
    }

    const float* APs[2] = {A, A2 ? A2 : A};
    const unsigned short* WhPs[2] = {Wh, W2h ? W2h : Wh};
    const unsigned short* WlPs[2] = {Wl, W2l ? W2l : Wl};
    int nt = K >> 5;
    int tnt = A2 ? (nt << 1) : nt;
    int arow = row0 + srow;
    int bcol = col0 + srow;

    // prefetch chunk 0
    float4 av0 = make_float4(0.f, 0.f, 0.f, 0.f), av1 = av0;
    if (arow < M) {
        av0 = *(const float4*)&APs[0][(size_t)arow * K + sk8];
        av1 = *(const float4*)&APs[0][(size_t)arow * K + sk8 + 4];
    }
    uint4 bvh = *(const uint4*)&WhPs[0][(size_t)bcol * K + sk8];
    uint4 bvl = *(const uint4*)&WlPs[0][(size_t)bcol * K + sk8];

    for (int tt = 0; tt < tnt; ++tt) {
        __syncthreads();
        {
            ushort4 h0, l0, h1, l1;
            h0.x = f2bf(av0.x); l0.x = f2bf(av0.x - bf2f(h0.x));
            h0.y = f2bf(av0.y); l0.y = f2bf(av0.y - bf2f(h0.y));
            h0.z = f2bf(av0.z); l0.z = f2bf(av0.z - bf2f(h0.z));
            h0.w = f2bf(av0.w); l0.w = f2bf(av0.w - bf2f(h0.w));
            h1.x = f2bf(av1.x); l1.x = f2bf(av1.x - bf2f(h1.x));
            h1.y = f2bf(av1.y); l1.y = f2bf(av1.y - bf2f(h1.y));
            h1.z = f2bf(av1.z); l1.z = f2bf(av1.z - bf2f(h1.z));
            h1.w = f2bf(av1.w); l1.w = f2bf(av1.w - bf2f(h1.w));
            *(ushort4*)&Ash[srow][sk8] = h0;
            *(ushort4*)&Ash[srow][sk8 + 4] = h1;
            *(ushort4*)&Asl[srow][sk8] = l0;
            *(ushort4*)&Asl[srow][sk8 + 4] = l1;
            *(uint4*)&Bsh[srow][sk8] = bvh;
            *(uint4*)&Bsl[srow][sk8] = bvl;
        }
        __syncthreads();
        if (tt + 1 < tnt) {
            int tp = tt + 1;
            int ps = (tp >= nt) ? 1 : 0;
            int k0 = (tp - (ps ? nt : 0)) << 5;
            av0 = make_float4(0.f, 0.f, 0.f, 0.f); av1 = av0;
            if (arow < M) {
                av0 = *(const float4*)&APs[ps][(size_t)arow * K + k0 + sk8];
                av1 = *(const float4*)&APs[ps][(size_t)arow * K + k0 + sk8 + 4];
            }
            bvh = *(const uint4*)&WhPs[ps][(size_t)bcol * K + k0 + sk8];
            bvl = *(const uint4*)&WlPs[ps][(size_t)bcol * K + k0 + sk8];
        }
        int afr = (w << 4) + (lane & 15);
        int afk = (lane >> 4) << 3;
        bf16x8 ah = *(const bf16x8*)&Ash[afr][afk];
        bf16x8 al = *(const bf16x8*)&Asl[afr][afk];
#pragma unroll
        for (int j = 0; j < 4; ++j) {
            int bfr = (j << 4) + (lane & 15);
            bf16x8 bh = *(const bf16x8*)&Bsh[bfr][afk];
            bf16x8 bl = *(const bf16x8*)&Bsl[bfr][afk];
            acc[j] = __builtin_amdgcn_mfma_f32_16x16x32_bf16(ah, bh, acc[j], 0, 0, 0);
            acc[j] = __builtin_amdgcn_mfma_f32_16x16x32_bf16(al, bh, acc[j], 0, 0, 0);
            acc[j] = __builtin_amdgcn_mfma_f32_16x16x32_bf16(ah, bl, acc[j], 0, 0, 0);
        }
    }

    // epilogue
#pragma unroll
    for (int j = 0; j < 4; ++j) {
        int col = col0 + (j << 4) + (lane & 15);
        float bb = bias[col];
#pragma unroll
        for (int i = 0; i < 4; ++i) {
            int row = row0 + (w << 4) + ((lane >> 4) << 2) + i;
            if (row < M) {
                float o = acc[j][i] + bb;
                if (ACT == 1) o = fmaxf(o, 0.f);
                else o = (o >= 0.f) ? o : 0.01f * o;
                C[(size_t)row * N + col] = o;
                if (Cb) Cb[(size_t)row * N + col] = f2bf(o);
            }
        }
    }
}

// ---------------------------------------------------------------- pooling

__global__ __launch_bounds__(128) void pool_kernel(const float* __restrict__ h,
                                                   const int* __restrict__ batch,
                                                   float* __restrict__ gsum) {
    int c = threadIdx.x;
    int r0 = blockIdx.x * 125, r1 = r0 + 125;
    float acc = 0.f;
    int cur = batch[r0];
    for (int r = r0; r < r1; ++r) {
        int b = batch[r];
        if (b != cur) {
            atomicAdd(&gsum[cur * OUT_D + c], acc);
            acc = 0.f;
            cur = b;
        }
        acc += h[(size_t)r * OUT_D + c];
    }
    atomicAdd(&gsum[cur * OUT_D + c], acc);
}

__global__ __launch_bounds__(256) void pooled_mm(const float* __restrict__ gsum,
                                                 const int* __restrict__ gcnt,
                                                 const float* __restrict__ ohw,
                                                 const float* __restrict__ ohb,
                                                 float* __restrict__ t2) {
    __shared__ float gm[OUT_D];
    int r = blockIdx.x;
    int c = threadIdx.x;
    if (c < OUT_D) {
        int ct = gcnt[r];
        gm[c] = gsum[r * OUT_D + c] / (float)(ct > 0 ? ct : 1);
    }
    __syncthreads();
    float acc = ohb[c];
    for (int k = 0; k < OUT_D; ++k) acc += gm[k] * ohw[k * HID + c];
    t2[r * HID + c] = acc;
}

__global__ __launch_bounds__(256) void finalize_kernel(const float* __restrict__ t2,
                                                       const float* __restrict__ gamma,
                                                       const float* __restrict__ beta,
                                                       const float* __restrict__ h1w,
                                                       const float* __restrict__ h1b,
                                                       float* __restrict__ out) {
    __shared__ float tl[NG][HID];
    int c = threadIdx.x;
    float mean = 0.f;
    for (int r = 0; r < NG; ++r) mean += t2[r * HID + c];
    mean *= (1.f / (float)NG);
    float var = 0.f;
    for (int r = 0; r < NG; ++r) {
        float d = t2[r * HID + c] - mean;
        var += d * d;
    }
    var *= (1.f / (float)NG);
    float sc = gamma[c] / sqrtf(var + 1e-5f);
    float sh = beta[c] - mean * sc;
    for (int r = 0; r < NG; ++r) {
        float v = t2[r * HID + c] * sc + sh;
        tl[r][c] = (v >= 0.f) ? v : 0.01f * v;
    }
    __syncthreads();
    int wid = c >> 6, lane = c & 63;
    float4 wv = *(const float4*)&h1w[lane << 2];
    float b0 = h1b[0];
    for (int row = wid; row < NG; row += 4) {
        float4 v = *(const float4*)&tl[row][lane << 2];
        float s = v.x * wv.x + v.y * wv.y + v.z * wv.z + v.w * wv.w;
#pragma unroll
        for (int off = 32; off >= 1; off >>= 1) s += __shfl_xor(s, off);
        if (lane == 0) out[row] = fmaxf(s + b0, 0.f);
    }
}

// ---------------------------------------------------------------- driver

extern "C" void kernel_launch(void* const* d_in, const int* in_sizes, int n_in,
                              void* d_out, int out_size, void* d_ws, size_t ws_size,
                              hipStream_t stream) {
    const float* x        = (const float*)d_in[0];
    const int*   ei       = (const int*)d_in[1];
    const float* eattr    = (const float*)d_in[2];
    const int*   batch    = (const int*)d_in[3];
    const float* prelin_w = (const float*)d_in[4];
    const float* prelin_b = (const float*)d_in[5];
    const float* c1_wl = (const float*)d_in[6],  *c1_bl = (const float*)d_in[7];
    const float* c1_wr = (const float*)d_in[8],  *c1_we = (const float*)d_in[9];
    const float* c1_be = (const float*)d_in[10];
    const float* c2_wl = (const float*)d_in[11], *c2_bl = (const float*)d_in[12];
    const float* c2_wr = (const float*)d_in[13], *c2_we = (const float*)d_in[14];
    const float* c2_be = (const float*)d_in[15];
    const float* c3_wl = (const float*)d_in[16], *c3_bl = (const float*)d_in[17];
    const float* c3_wr = (const float*)d_in[18], *c3_we = (const float*)d_in[19];
    const float* c3_be = (const float*)d_in[20];
    const float* hh1_w = (const float*)d_in[21], *hh1_b = (const float*)d_in[22];
    const float* hh2_w = (const float*)d_in[23], *hh2_b = (const float*)d_in[24];
    const float* oo_w  = (const float*)d_in[25], *oo_b  = (const float*)d_in[26];
    const float* oh_w  = (const float*)d_in[27], *oh_b  = (const float*)d_in[28];
    const float* h1_w  = (const float*)d_in[29], *h1_b  = (const float*)d_in[30];
    const float* bn_g  = (const float*)d_in[31], *bn_b  = (const float*)d_in[32];
    float* out = (float*)d_out;

    const int* srcp = ei;
    const int* dstp = ei + N_EDGES;

    // workspace (word = 4 B): activations fp32 (R10 dataflow) + bf16 gather
    // table + double-bf16 weight planes.  Total ~10.16M words = 40.7 MB
    // (< proven ws >= 48.9 MB).
    float* ws = (float*)d_ws;
    float*          hA    = ws;                                // [10000,256] f32  [0, 2.56M)
    float*          hB    = ws + 2560000;                      // [10000,256] f32  [2.56M, 5.12M)
    float*          AGG   = ws + 5120000;                      // [10000,256] f32  [5.12M, 7.68M)
    unsigned short* h16   = (unsigned short*)(ws + 7680000);   // [10000,256] bf16 [7.68M, 8.96M)
    unsigned short* wth   = (unsigned short*)(ws + 8960000);   // hi plane, 507904 shorts
    unsigned short* wtl   = (unsigned short*)(ws + 9213952);   // lo plane, 507904 shorts
    unsigned short* wh_pre = wth;                // [256][128]  32768 shorts
    unsigned short* wh_c1l = wh_pre + 32768;     // [256][256]  65536
    unsigned short* wh_c1r = wh_c1l + 65536;
    unsigned short* wh_hh1 = wh_c1r + 65536;
    unsigned short* wh_c2l = wh_hh1 + 65536;
    unsigned short* wh_c2r = wh_c2l + 65536;
    unsigned short* wh_hh2 = wh_c2r + 65536;
    unsigned short* wh_c3l = wh_hh2 + 65536;     // [128][256]  32768
    unsigned short* wh_c3r = wh_c3l + 32768;
    unsigned short* wh_oo  = wh_c3r + 32768;     // [128][128]  16384
    unsigned short* wl_pre = wtl;
    unsigned short* wl_c1l = wl_pre + 32768;
    unsigned short* wl_c1r = wl_c1l + 65536;
    unsigned short* wl_hh1 = wl_c1r + 65536;
    unsigned short* wl_c2l = wl_hh1 + 65536;
    unsigned short* wl_c2r = wl_c2l + 65536;
    unsigned short* wl_hh2 = wl_c2r + 65536;
    unsigned short* wl_c3l = wl_hh2 + 65536;
    unsigned short* wl_c3r = wl_c3l + 32768;
    unsigned short* wl_oo  = wl_c3r + 32768;
    float* tail  = ws + 9467904;                 // wtl ends at 9213952+253952
    float* t2    = tail;                          // [64,256]
    float* gsum  = t2 + NG * HID;                 // [64,128]
    int*   gcnt  = (int*)(gsum + NG * OUT_D);     // [64]
    int*   rowptr = gcnt + NG;                    // [10001]
    int*   cnt   = rowptr + (N_NODES + 1);        // [10000]
    int*   fill  = cnt + N_NODES;                 // [10000]
    int*   srcs  = fill + N_NODES;                // [320000]
    float* attrs = (float*)(srcs + N_EDGES);      // [320000]

    zero_kernel<<<(2 * N_NODES + 255) / 256, 256, 0, stream>>>((unsigned int*)cnt, 2 * N_NODES);
    zero_kernel<<<(NG * OUT_D + NG + 255) / 256, 256, 0, stream>>>((unsigned int*)gsum, NG * OUT_D + NG);

    // weight split (hi/lo double-bf16), one launch
    W10 wp;
    wp.w[0] = prelin_w; wp.oh[0] = wh_pre; wp.ol[0] = wl_pre; wp.K[0] = DIM_IN; wp.N[0] = HID;
    wp.w[1] = c1_wl;    wp.oh[1] = wh_c1l; wp.ol[1] = wl_c1l; wp.K[1] = HID;    wp.N[1] = HID;
    wp.w[2] = c1_wr;    wp.oh[2] = wh_c1r; wp.ol[2] = wl_c1r; wp.K[2] = HID;    wp.N[2] = HID;
    wp.w[3] = hh1_w;    wp.oh[3] = wh_hh1; wp.ol[3] = wl_hh1; wp.K[3] = HID;    wp.N[3] = HID;
    wp.w[4] = c2_wl;    wp.oh[4] = wh_c2l; wp.ol[4] = wl_c2l; wp.K[4] = HID;    wp.N[4] = HID;
    wp.w[5] = c2_wr;    wp.oh[5] = wh_c2r; wp.ol[5] = wl_c2r; wp.K[5] = HID;    wp.N[5] = HID;
    wp.w[6] = hh2_w;    wp.oh[6] = wh_hh2; wp.ol[6] = wl_hh2; wp.K[6] = HID;    wp.N[6] = HID;
    wp.w[7] = c3_wl;    wp.oh[7] = wh_c3l; wp.ol[7] = wl_c3l; wp.K[7] = HID;    wp.N[7] = OUT_D;
    wp.w[8] = c3_wr;    wp.oh[8] = wh_c3r; wp.ol[8] = wl_c3r; wp.K[8] = HID;    wp.N[8] = OUT_D;
    wp.w[9] = oo_w;     wp.oh[9] = wh_oo;  wp.ol[9] = wl_oo;  wp.K[9] = OUT_D;  wp.N[9] = OUT_D;
    w2bt_kernel<<<dim3(16, 16, 10), 256, 0, stream>>>(wp);

    // CSR build + group counts
    hist_kernel<<<(N_EDGES + 255) / 256, 256, 0, stream>>>(dstp, cnt, N_EDGES);
    scan_kernel<<<1, 1024, 0, stream>>>(cnt, rowptr, N_NODES);
    scatter_kernel<<<(N_EDGES + 255) / 256, 256, 0, stream>>>(srcp, dstp, eattr, rowptr,
                                                              fill, srcs, attrs, N_EDGES);
    gcount_kernel<<<1, 128, 0, stream>>>(batch, gcnt);

    dim3 blk(256);
    dim3 g256(HID / 64, (N_NODES + 63) / 64);     // N=256: 4 x 157
    dim3 g128(OUT_D / 64, (N_NODES + 63) / 64);   // N=128: 2 x 157
    int agrid = N_NODES / 4;

    // h = relu(x @ prelin_w + b)            -> hA (f32) + h16 (gather table)
    gemmx<1><<<g256, blk, 0, stream>>>(x, wh_pre, wl_pre, nullptr, nullptr, nullptr,
                                       prelin_b, hA, h16, N_NODES, HID, DIM_IN);
    // conv1: relu(AGG@Wl + h@Wr + bl)       -> hB
    agg16_kernel<<<agrid, blk, 0, stream>>>(h16, srcs, attrs, rowptr, c1_we, c1_be, AGG);
    gemmx<1><<<g256, blk, 0, stream>>>(AGG, wh_c1l, wl_c1l, hA, wh_c1r, wl_c1r,
                                       c1_bl, hB, nullptr, N_NODES, HID, HID);
    // hh1: leaky(hB @ hh1_w + b)            -> hA + h16
    gemmx<2><<<g256, blk, 0, stream>>>(hB, wh_hh1, wl_hh1, nullptr, nullptr, nullptr,
                                       hh1_b, hA, h16, N_NODES, HID, HID);
    // conv2                                  -> hB
    agg16_kernel<<<agrid, blk, 0, stream>>>(h16, srcs, attrs, rowptr, c2_we, c2_be, AGG);
    gemmx<1><<<g256, blk, 0, stream>>>(AGG, wh_c2l, wl_c2l, hA, wh_c2r, wl_c2r,
                                       c2_bl, hB, nullptr, N_NODES, HID, HID);
    // hh2                                    -> hA + h16
    gemmx<2><<<g256, blk, 0, stream>>>(hB, wh_hh2, wl_hh2, nullptr, nullptr, nullptr,
                                       hh2_b, hA, h16, N_NODES, HID, HID);
    // conv3 (HID -> OUT)                     -> hB [10000,128]
    agg16_kernel<<<agrid, blk, 0, stream>>>(h16, srcs, attrs, rowptr, c3_we, c3_be, AGG);
    gemmx<1><<<g128, blk, 0, stream>>>(AGG, wh_c3l, wl_c3l, hA, wh_c3r, wl_c3r,
                                       c3_bl, hB, nullptr, N_NODES, OUT_D, HID);
    // oo: leaky(hB @ oo_w + b)               -> hA (f32, for pooling)
    gemmx<2><<<g128, blk, 0, stream>>>(hB, wh_oo, wl_oo, nullptr, nullptr, nullptr,
                                       oo_b, hA, nullptr, N_NODES, OUT_D, OUT_D);

    // global mean pool + head
    pool_kernel<<<80, 128, 0, stream>>>(hA, batch, gsum);
    pooled_mm<<<NG, 256, 0, stream>>>(gsum, gcnt, oh_w, oh_b, t2);
    finalize_kernel<<<1, 256, 0, stream>>>(t2, bn_g, bn_b, h1_w, h1_b, out);
}